// Round 7
// baseline (303.002 us; speedup 1.0000x reference)
//
#include <hip/hip_runtime.h>
#include <math.h>

#define C_DIM 512
#define N_DIM 4096
#define CN (C_DIM * N_DIM)
#define SZO (N_DIM * C_DIM)          // 2,097,152 (pixel x channel)
#define NN ((size_t)N_DIM * N_DIM)
#define NN_TOT ((long long)N_DIM * N_DIM)

typedef __attribute__((ext_vector_type(4))) float f32x4;
typedef __attribute__((ext_vector_type(8))) short short8;

__device__ __forceinline__ ushort f2bf(float f) {
    unsigned u = __float_as_uint(f);
    unsigned r = u + 0x7FFFu + ((u >> 16) & 1u);
    return (ushort)(r >> 16);
}
__device__ __forceinline__ float bf2f(ushort h) {
    return __uint_as_float((unsigned)h << 16);
}

__device__ __forceinline__ void gload16(const void* g, void* l) {
    __builtin_amdgcn_global_load_lds(
        (const __attribute__((address_space(1))) void*)g,
        (__attribute__((address_space(3))) void*)l, 16, 0, 0);
}

// ---------------------------------------------------------------------------
// setup_all: one launch, three independent roles.
//  id <  1024 : tconv  — x/y f32 [512][4096] -> xbT/ybT bf16 [4096][512]
//  id <  1792 : cvtw3  — Wv/W1/W2 f32 -> bf16
//  id <  2048 : qkraw2 — Q&K proj raw f32 split-K x2, PX[kz][src][128][4096]
//               (both Wq and Wk rows per block; X read once; fmaf order per
//                output element identical to previous qkraw -> bitwise-same PX)
// ---------------------------------------------------------------------------
__global__ __launch_bounds__(256) void setup_all(
    const float* __restrict__ x, const float* __restrict__ y,
    ushort* __restrict__ xbT, ushort* __restrict__ ybT,
    const float* __restrict__ Wv, const float* __restrict__ W1,
    const float* __restrict__ W2, ushort* __restrict__ Wvb,
    ushort* __restrict__ W1b, ushort* __restrict__ W2b,
    const float* __restrict__ Wq, const float* __restrict__ Wk,
    float* __restrict__ PX)
{
    __shared__ float t[64][65];
    __shared__ float Asw[16][130];
    __shared__ float Bsx[16][65];
    const int id = blockIdx.x;
    const int tid = threadIdx.x;

    if (id < 1024) {            // ---- tconv ----
        const int bx = id & 63, by = (id >> 6) & 7, bz = id >> 9;
        const float* X = bz ? y : x;
        ushort* XT = bz ? ybT : xbT;
        const int c0 = bx * 64, r0 = by * 64;
        const int ty = tid >> 4, tx = tid & 15;
        #pragma unroll
        for (int i = 0; i < 4; ++i) {
            int r = ty + i * 16;
            float4 v = *(const float4*)&X[(size_t)(r0 + r) * N_DIM + c0 + tx * 4];
            t[r][tx * 4 + 0] = v.x; t[r][tx * 4 + 1] = v.y;
            t[r][tx * 4 + 2] = v.z; t[r][tx * 4 + 3] = v.w;
        }
        __syncthreads();
        #pragma unroll
        for (int i = 0; i < 4; ++i) {
            int nn = ty + i * 16;
            ushort4 o;
            o.x = f2bf(t[tx * 4 + 0][nn]); o.y = f2bf(t[tx * 4 + 1][nn]);
            o.z = f2bf(t[tx * 4 + 2][nn]); o.w = f2bf(t[tx * 4 + 3][nn]);
            *(ushort4*)&XT[(size_t)(c0 + nn) * C_DIM + r0 + tx * 4] = o;
        }
        return;
    }
    if (id < 1792) {            // ---- cvtw3 ----
        const int i2 = id - 1024;
        const int bx = i2 & 255, by = i2 >> 8;
        const float* in  = (by == 0) ? Wv : (by == 1) ? W1 : W2;
        ushort*      out = (by == 0) ? Wvb : (by == 1) ? W1b : W2b;
        int i = (bx * 256 + tid) * 4;
        float4 v = *(const float4*)&in[i];
        ushort4 o = { f2bf(v.x), f2bf(v.y), f2bf(v.z), f2bf(v.w) };
        *(ushort4*)&out[i] = o;
        return;
    }
    // ---- qkraw2 ----
    {
        const int i3 = id - 1792;
        const int ntile = i3 & 63;
        const int srcT  = (i3 >> 6) & 1;
        const int kz    = i3 >> 7;
        const float* X = srcT ? y : x;
        const int n0 = ntile * 64;
        const int ty = tid >> 4, tx = tid & 15;
        float accQ[4][4] = {}, accK[4][4] = {};
        const int kbase = kz * 256;

        for (int k0 = kbase; k0 < kbase + 256; k0 += 16) {
            #pragma unroll
            for (int i = 0; i < 2; ++i) {
                int wi = tid + i * 256;       // 0..511
                int mm = wi >> 2;             // 0..127
                int kq = (wi & 3) * 4;
                const float* Wp = (mm < 64) ? &Wq[(size_t)mm * 512]
                                            : &Wk[(size_t)(mm - 64) * 512];
                float4 w4 = *(const float4*)&Wp[k0 + kq];
                Asw[kq + 0][mm] = w4.x; Asw[kq + 1][mm] = w4.y;
                Asw[kq + 2][mm] = w4.z; Asw[kq + 3][mm] = w4.w;
            }
            {
                int kk = tid >> 4, nq = (tid & 15) * 4;
                *(float4*)&Bsx[kk][nq] = *(const float4*)&X[(size_t)(k0 + kk) * N_DIM + n0 + nq];
            }
            __syncthreads();
            #pragma unroll
            for (int kk = 0; kk < 16; ++kk) {
                float aq[4], ak[4], b[4];
                #pragma unroll
                for (int r = 0; r < 4; ++r) { aq[r] = Asw[kk][ty * 4 + r]; ak[r] = Asw[kk][64 + ty * 4 + r]; }
                #pragma unroll
                for (int c = 0; c < 4; ++c) b[c] = Bsx[kk][tx * 4 + c];
                #pragma unroll
                for (int r = 0; r < 4; ++r)
                    #pragma unroll
                    for (int c = 0; c < 4; ++c) {
                        accQ[r][c] = fmaf(aq[r], b[c], accQ[r][c]);
                        accK[r][c] = fmaf(ak[r], b[c], accK[r][c]);
                    }
            }
            __syncthreads();
        }
        float* dst = PX + ((size_t)(kz * 2 + srcT) * 128) * N_DIM;
        #pragma unroll
        for (int r = 0; r < 4; ++r) {
            float4 oq = make_float4(accQ[r][0], accQ[r][1], accQ[r][2], accQ[r][3]);
            *(float4*)&dst[(size_t)(ty * 4 + r) * N_DIM + n0 + tx * 4] = oq;
            float4 ok = make_float4(accK[r][0], accK[r][1], accK[r][2], accK[r][3]);
            *(float4*)&dst[(size_t)(64 + ty * 4 + r) * N_DIM + n0 + tx * 4] = ok;
        }
    }
}

// ---------------------------------------------------------------------------
// Reduce PX partials, apply mask/bias/scale per use-case, split hi/lo bf16x3,
// write QF0/KF0/QF1/KF1 in score-fragment layout [256][6][64][8].
// ---------------------------------------------------------------------------
__global__ __launch_bounds__(256) void qkfinish(
    const float* __restrict__ PX,
    const float* __restrict__ s_m, const float* __restrict__ q_m,
    const float* __restrict__ bq, const float* __restrict__ bk,
    ushort* __restrict__ QF0, ushort* __restrict__ KF0,
    ushort* __restrict__ QF1, ushort* __restrict__ KF1)
{
    int gid = blockIdx.x * 256 + threadIdx.x;
    int lane = gid & 63;
    int rest = gid >> 6;
    int blk = rest & 255;
    int tensor = rest >> 8;       // 0..3
    int fr = lane & 15, quad = lane >> 4;
    int n = blk * 16 + fr;

    int srcT, rowbase, isQ;
    const float* bias;
    ushort* dst;
    float mv, scale;
    if (tensor == 0)      { srcT = 0; rowbase = 0;  isQ = 1; bias = bq; dst = QF0; scale = 0.125f; mv = s_m[n]; }
    else if (tensor == 1) { srcT = 1; rowbase = 64; isQ = 0; bias = bk; dst = KF0; scale = 1.0f;   mv = (q_m[n] > 0.8f) ? 1.0f : 0.0f; }
    else if (tensor == 2) { srcT = 1; rowbase = 0;  isQ = 1; bias = bq; dst = QF1; scale = 0.125f; mv = (q_m[n] > 0.8f) ? 1.0f : 0.0f; }
    else                  { srcT = 0; rowbase = 64; isQ = 0; bias = bk; dst = KF1; scale = 1.0f;   mv = 1.0f; }

    ushort hi0[8], lo0[8], hi1[8], lo1[8];
    #pragma unroll
    for (int j = 0; j < 8; ++j) {
        int d0 = quad * 8 + j, d1 = 32 + d0;
        float v0 = 0.0f, v1 = 0.0f;
        #pragma unroll
        for (int kz = 0; kz < 2; ++kz) {
            size_t base = ((size_t)(kz * 2 + srcT) * 128 + rowbase);
            v0 += PX[(base + d0) * N_DIM + n];
            v1 += PX[(base + d1) * N_DIM + n];
        }
        v0 = (v0 * mv + bias[d0]) * scale;
        v1 = (v1 * mv + bias[d1]) * scale;
        hi0[j] = f2bf(v0); lo0[j] = f2bf(v0 - bf2f(hi0[j]));
        hi1[j] = f2bf(v1); lo1[j] = f2bf(v1 - bf2f(hi1[j]));
    }
    auto wr8 = [&](int kstep, const ushort* v) {
        size_t base = ((size_t)(blk * 6 + kstep) * 64 + lane) * 8;
        *(ushort4*)&dst[base]     = *(const ushort4*)&v[0];
        *(ushort4*)&dst[base + 4] = *(const ushort4*)&v[4];
    };
    wr8(0, hi0); wr8(1, hi1);
    if (isQ) { wr8(2, hi0); wr8(3, hi1); wr8(4, lo0); wr8(5, lo1); }
    else     { wr8(2, lo0); wr8(3, lo1); wr8(4, hi0); wr8(5, hi1); }
}

// shared MFMA core for the two score passes (identical arithmetic order!)
__device__ __forceinline__ void scores_mfma(
    const ushort* __restrict__ QF, const ushort* __restrict__ KF,
    int m0, int n0, int wr, int wc, int lane, f32x4 acc[4][4])
{
    const int blkA0 = (m0 + wr) >> 4;
    const int blkB0 = (n0 + wc) >> 4;
    #pragma unroll
    for (int s = 0; s < 6; ++s) {
        short8 af[4], bf[4];
        #pragma unroll
        for (int mr = 0; mr < 4; ++mr)
            af[mr] = *(const short8*)&QF[((size_t)((blkA0 + mr) * 6 + s) * 64 + lane) * 8];
        #pragma unroll
        for (int nc = 0; nc < 4; ++nc)
            bf[nc] = *(const short8*)&KF[((size_t)((blkB0 + nc) * 6 + s) * 64 + lane) * 8];
        #pragma unroll
        for (int mr = 0; mr < 4; ++mr)
            #pragma unroll
            for (int nc = 0; nc < 4; ++nc)
                acc[mr][nc] = __builtin_amdgcn_mfma_f32_16x16x32_bf16(
                    af[mr], bf[nc], acc[mr][nc], 0, 0, 0);
    }
}

// ---------------------------------------------------------------------------
// vproj_p1: one launch, two independent roles.
//  id < 256  : V projection, bf16 MFMA NT <128,128>, both branches
//  id >= 256 : scores pass 1 (global max/min/sum partials + per-row max)
// V-proj blocks first so they backfill CUs while pass1 floods the machine.
// ---------------------------------------------------------------------------
__global__ __launch_bounds__(256) void vproj_p1(
    const ushort* __restrict__ Wvb,
    const ushort* __restrict__ xbT, const ushort* __restrict__ ybT,
    const float* __restrict__ bv, const float* __restrict__ q_m,
    ushort* __restrict__ Vb,
    const ushort* __restrict__ QF0, const ushort* __restrict__ KF0,
    const ushort* __restrict__ QF1, const ushort* __restrict__ KF1,
    float* __restrict__ part, float* __restrict__ rowmaxp)
{
    __shared__ ushort As[2][128 * 32];
    __shared__ ushort Bs[2][128 * 32];
    __shared__ float wrm[2][128];
    __shared__ float red[256];
    const int id = blockIdx.x;
    const int tid = threadIdx.x;
    const int lane = tid & 63;
    const int wid  = tid >> 6;

    if (id < 256) {
        // ================= V-proj path: Vb[br] = Wv . B + bv ==============
        const int bxn = id & 31;          // n-tile (N=4096)
        const int bym = (id >> 5) & 3;    // m-tile (M=512)
        const int br  = id >> 7;
        const ushort* A = Wvb;
        const ushort* B = br ? xbT : ybT;
        const int m0 = bym * 128, n0 = bxn * 128;
        const int wr = (wid >> 1) * 64, wc = (wid & 1) * 64;
        const int lrow = lane >> 2;
        const int kbl  = lane & 3;
        const int K = 512;

        auto stage = [&](int buf, int t) {
            #pragma unroll
            for (int c = wid; c < 16; c += 4) {
                if (c < 8) {
                    int r = c * 16 + lrow;
                    int kb = kbl ^ ((r >> 1) & 3);
                    gload16(A + (size_t)(m0 + r) * K + t * 32 + kb * 8, &As[buf][c * 512]);
                } else {
                    int cb = c - 8;
                    int r = cb * 16 + lrow;
                    int kb = kbl ^ ((r >> 1) & 3);
                    gload16(B + (size_t)(n0 + r) * K + t * 32 + kb * 8, &Bs[buf][cb * 512]);
                }
            }
        };

        f32x4 acc[4][4] = {};
        const int fr = lane & 15;
        const int kq = lane >> 4;
        stage(0, 0);
        asm volatile("s_waitcnt vmcnt(0)" ::: "memory");
        __syncthreads();
        int cur = 0;
        for (int t = 0; t < 16; ++t) {
            if (t + 1 < 16) stage(cur ^ 1, t + 1);
            short8 af[4], bf[4];
            #pragma unroll
            for (int mr = 0; mr < 4; ++mr) {
                int rA = wr + mr * 16 + fr;
                af[mr] = *(const short8*)&As[cur][rA * 32 + (kq ^ ((rA >> 1) & 3)) * 8];
            }
            #pragma unroll
            for (int nc = 0; nc < 4; ++nc) {
                int rB = wc + nc * 16 + fr;
                bf[nc] = *(const short8*)&Bs[cur][rB * 32 + (kq ^ ((rB >> 1) & 3)) * 8];
            }
            #pragma unroll
            for (int mr = 0; mr < 4; ++mr)
                #pragma unroll
                for (int nc = 0; nc < 4; ++nc)
                    acc[mr][nc] = __builtin_amdgcn_mfma_f32_16x16x32_bf16(
                        af[mr], bf[nc], acc[mr][nc], 0, 0, 0);
            asm volatile("s_waitcnt vmcnt(0)" ::: "memory");
            __syncthreads();
            cur ^= 1;
        }
        const int orow = (lane >> 4) * 4;
        const int ocol = lane & 15;
        float mcol[4];
        #pragma unroll
        for (int nc = 0; nc < 4; ++nc) {
            int gn = n0 + wc + nc * 16 + ocol;
            mcol[nc] = br ? 1.0f : ((q_m[gn] > 0.8f) ? 1.0f : 0.0f);
        }
        ushort* Obf = Vb + (size_t)br * CN;
        #pragma unroll
        for (int mr = 0; mr < 4; ++mr)
            #pragma unroll
            for (int j = 0; j < 4; ++j) {
                int gm = m0 + wr + mr * 16 + orow + j;
                float brow = bv[gm];
                #pragma unroll
                for (int nc = 0; nc < 4; ++nc) {
                    int gn = n0 + wc + nc * 16 + ocol;
                    float v = acc[mr][nc][j] * mcol[nc] + brow;
                    Obf[(size_t)gm * N_DIM + gn] = f2bf(v);
                }
            }
        return;
    }

    // ================= scores pass 1 path =================================
    {
        const int p = id - 256;
        const int bxn = p & 31;           // n-tile
        const int bym = (p >> 5) & 31;    // m-tile
        const int br  = p >> 10;
        const ushort* QF = br ? QF1 : QF0;
        const ushort* KF = br ? KF1 : KF0;
        float* pt = part + (size_t)br * 3072;
        float* rmp = rowmaxp + (size_t)br * 131072;

        const int m0 = bym * 128, n0 = bxn * 128;
        const int wr = (wid >> 1) * 64, wc = (wid & 1) * 64;
        f32x4 acc[4][4] = {};
        scores_mfma(QF, KF, m0, n0, wr, wc, lane, acc);

        float lmax = -3.4e38f, lmin = 3.4e38f, lsum = 0.0f;
        float rmx[4][4];
        #pragma unroll
        for (int mr = 0; mr < 4; ++mr)
            #pragma unroll
            for (int j = 0; j < 4; ++j) rmx[mr][j] = -3.4e38f;
        #pragma unroll
        for (int mr = 0; mr < 4; ++mr)
            #pragma unroll
            for (int nc = 0; nc < 4; ++nc)
                #pragma unroll
                for (int j = 0; j < 4; ++j) {
                    float v = acc[mr][nc][j];
                    lsum += v; lmax = fmaxf(lmax, v); lmin = fminf(lmin, v);
                    rmx[mr][j] = fmaxf(rmx[mr][j], v);
                }
        #pragma unroll
        for (int m = 1; m < 16; m <<= 1)
            #pragma unroll
            for (int mr = 0; mr < 4; ++mr)
                #pragma unroll
                for (int j = 0; j < 4; ++j)
                    rmx[mr][j] = fmaxf(rmx[mr][j], __shfl_xor(rmx[mr][j], m, 64));

        const int orow = (lane >> 4) * 4;
        if ((lane & 15) == 0) {
            #pragma unroll
            for (int mr = 0; mr < 4; ++mr)
                #pragma unroll
                for (int j = 0; j < 4; ++j)
                    wrm[wid & 1][wr + mr * 16 + orow + j] = rmx[mr][j];
        }
        __syncthreads();
        if (tid < 128) {
            float v = fmaxf(wrm[0][tid], wrm[1][tid]);
            rmp[(size_t)bxn * 4096 + m0 + tid] = v;
        }

        const int bid = bym * 32 + bxn;
        __syncthreads();
        red[tid] = lmax; __syncthreads();
        for (int s = 128; s > 0; s >>= 1) { if (tid < s) red[tid] = fmaxf(red[tid], red[tid + s]); __syncthreads(); }
        if (tid == 0) pt[bid] = red[0];
        __syncthreads();
        red[tid] = lmin; __syncthreads();
        for (int s = 128; s > 0; s >>= 1) { if (tid < s) red[tid] = fminf(red[tid], red[tid + s]); __syncthreads(); }
        if (tid == 0) pt[1024 + bid] = red[0];
        __syncthreads();
        red[tid] = lsum; __syncthreads();
        for (int s = 128; s > 0; s >>= 1) { if (tid < s) red[tid] += red[tid + s]; __syncthreads(); }
        if (tid == 0) pt[2048 + bid] = red[0];
    }
}

// ---------------------------------------------------------------------------
// pass 2 (z-batched): folded stats_fin2 (every block redundantly computes thr
// with the identical reduction order -> bitwise-same) + folded row_fin;
// recompute scores, write e = exp(s-m) bf16 + rowsum partials.
// ---------------------------------------------------------------------------
__global__ __launch_bounds__(256) void scores_pass2(
    const ushort* __restrict__ QF0, const ushort* __restrict__ KF0,
    const ushort* __restrict__ QF1, const ushort* __restrict__ KF1,
    const float* __restrict__ part, const float* __restrict__ rowmaxp,
    ushort* __restrict__ Pe, float* __restrict__ rowsump)
{
    const int br = blockIdx.z;
    const ushort* QF = br ? QF1 : QF0;
    const ushort* KF = br ? KF1 : KF0;
    ushort* P = Pe + (size_t)br * NN;
    rowsump += (size_t)br * 131072;
    rowmaxp += (size_t)br * 131072;
    const float* pp = part + (size_t)br * 3072;

    const int tid = threadIdx.x;
    const int lane = tid & 63, wid = tid >> 6;
    const int m0 = blockIdx.y * 128, n0 = blockIdx.x * 128;
    const int wr = (wid >> 1) * 64, wc = (wid & 1) * 64;

    // ---- folded stats_fin2 (identical order to old kernel) ----
    __shared__ float smx[256], smn[256];
    __shared__ double ssm[256];
    {
        float m1 = -3.4e38f, m2 = 3.4e38f; double s = 0.0;
        for (int i = tid; i < 1024; i += 256) {
            m1 = fmaxf(m1, pp[i]);
            m2 = fminf(m2, pp[1024 + i]);
            s += (double)pp[2048 + i];
        }
        smx[tid] = m1; smn[tid] = m2; ssm[tid] = s;
        __syncthreads();
        for (int st = 128; st > 0; st >>= 1) {
            if (tid < st) {
                smx[tid] = fmaxf(smx[tid], smx[tid + st]);
                smn[tid] = fminf(smn[tid], smn[tid + st]);
                ssm[tid] += ssm[tid + st];
            }
            __syncthreads();
        }
    }
    const float stat = (br == 0) ? smx[0] : smn[0];
    const float mean = (float)(ssm[0] / (double)NN_TOT);
    const float thr = 0.5f * (stat + mean);

    // ---- folded row_fin: rowm for this block's 128 rows ----
    __shared__ float rowmL[128];
    if (tid < 128) {
        int r = m0 + tid;
        float m = -3.4e38f;
        #pragma unroll 8
        for (int b = 0; b < 32; ++b)
            m = fmaxf(m, rowmaxp[(size_t)b * 4096 + r]);
        rowmL[tid] = (m >= thr) ? m : -1e30f;
    }
    __syncthreads();

    f32x4 acc[4][4] = {};
    scores_mfma(QF, KF, m0, n0, wr, wc, lane, acc);

    const int orow = (lane >> 4) * 4;
    const int ocol = lane & 15;
    float rm[4][4], rs[4][4];
    #pragma unroll
    for (int mr = 0; mr < 4; ++mr)
        #pragma unroll
        for (int j = 0; j < 4; ++j) {
            rm[mr][j] = rowmL[wr + mr * 16 + orow + j];
            rs[mr][j] = 0.0f;
        }
    #pragma unroll
    for (int mr = 0; mr < 4; ++mr)
        #pragma unroll
        for (int nc = 0; nc < 4; ++nc)
            #pragma unroll
            for (int j = 0; j < 4; ++j) {
                float s = acc[mr][nc][j];
                float m = rm[mr][j];
                float e = (s < thr) ? 0.0f : __expf(s - m);
                if (m < -1e29f) e = 1.0f;          // fully-masked row -> uniform
                ushort h = f2bf(e);
                rs[mr][j] += bf2f(h);
                P[(size_t)(m0 + wr + mr * 16 + orow + j) * N_DIM
                  + n0 + wc + nc * 16 + ocol] = h;
            }
    #pragma unroll
    for (int m = 1; m < 16; m <<= 1)
        #pragma unroll
        for (int mr = 0; mr < 4; ++mr)
            #pragma unroll
            for (int j = 0; j < 4; ++j)
                rs[mr][j] += __shfl_xor(rs[mr][j], m, 64);

    __shared__ float wrs[2][128];
    if ((lane & 15) == 0) {
        #pragma unroll
        for (int mr = 0; mr < 4; ++mr)
            #pragma unroll
            for (int j = 0; j < 4; ++j)
                wrs[wid & 1][wr + mr * 16 + orow + j] = rs[mr][j];
    }
    __syncthreads();
    if (tid < 128)
        rowsump[(size_t)blockIdx.x * 4096 + m0 + tid] =
            wrs[0][tid] + wrs[1][tid];
}

// ---------------------------------------------------------------------------
// Generic bf16 MFMA NT GEMM (round-5 proven: 128-row tiles, XOR swizzle,
// conflict-free). Branch-batched: z = br*nkz + kz.
// ---------------------------------------------------------------------------
template<int BM, int BN>
__global__ __launch_bounds__(256) void mfma_g(
    const ushort* __restrict__ A0, const ushort* __restrict__ A1,
    const ushort* __restrict__ B0, const ushort* __restrict__ B1,
    void* __restrict__ Out, size_t outBrStride,
    int M, int N, int K, int kLen, int nkz, int swapxy,
    const float* __restrict__ bias, int biasMode,
    const float* __restrict__ mask0, int mm0,
    const float* __restrict__ mask1, int mm1,
    int doRelu, int outBf16, float* __restrict__ lnp)
{
    constexpr int WAVES_M = BM / 64;
    constexpr int WAVES_N = 4 / WAVES_M;
    constexpr int WN = BN / WAVES_N;
    constexpr int FM = 4;
    constexpr int FN = WN / 16;
    constexpr int NCHUNK = (BM + BN) / 16;

    __shared__ ushort As[2][BM * 32];
    __shared__ ushort Bs[2][BN * 32];
    const int tid  = threadIdx.x;
    const int lane = tid & 63;
    const int wid  = tid >> 6;
    const int z  = blockIdx.z;
    const int br = z / nkz;
    const int kz = z % nkz;
    const ushort* A = br ? A1 : A0;
    const ushort* B = br ? B1 : B0;
    const float* mask = br ? mask1 : mask0;
    const int maskMode = br ? mm1 : mm0;

    const int bxm = swapxy ? blockIdx.x : blockIdx.y;
    const int bxn = swapxy ? blockIdx.y : blockIdx.x;
    const int m0 = bxm * BM, n0 = bxn * BN;
    const int wm = wid / WAVES_N, wn = wid % WAVES_N;
    const int wr = wm * 64, wc = wn * WN;
    const int kOff = kz * kLen;
    const int lrow = lane >> 2;
    const int kbl  = lane & 3;

    auto stage = [&](int buf, int t) {
        #pragma unroll
        for (int c = wid; c < NCHUNK; c += 4) {
            if (c < BM / 16) {
                int r = c * 16 + lrow;
                int kb = kbl ^ ((r >> 1) & 3);
                gload16(A + (size_t)(m0 + r) * K + kOff + t * 32 + kb * 8,
                        &As[buf][c * 512]);
            } else {
                int cb = c - BM / 16;
                int r = cb * 16 + lrow;
                int kb = kbl ^ ((r >> 1) & 3);
                gload16(B + (size_t)(n0 + r) * K + kOff + t * 32 + kb * 8,
                        &Bs[buf][cb * 512]);
            }
        }
    };

    f32x4 acc[FM][FN] = {};
    const int fr = lane & 15;
    const int kq = lane >> 4;
    const int nt = kLen / 32;

    stage(0, 0);
    asm volatile("s_waitcnt vmcnt(0)" ::: "memory");
    __syncthreads();
    int cur = 0;
    for (int t = 0; t < nt; ++t) {
        if (t + 1 < nt) stage(cur ^ 1, t + 1);
        short8 af[FM], bf[FN];
        #pragma unroll
        for (int mr = 0; mr < FM; ++mr) {
            int rA = wr + mr * 16 + fr;
            af[mr] = *(const short8*)&As[cur][rA * 32 + (kq ^ ((rA >> 1) & 3)) * 8];
        }
        #pragma unroll
        for (int nc = 0; nc < FN; ++nc) {
            int rB = wc + nc * 16 + fr;
            bf[nc] = *(const short8*)&Bs[cur][rB * 32 + (kq ^ ((rB >> 1) & 3)) * 8];
        }
        #pragma unroll
        for (int mr = 0; mr < FM; ++mr)
            #pragma unroll
            for (int nc = 0; nc < FN; ++nc)
                acc[mr][nc] = __builtin_amdgcn_mfma_f32_16x16x32_bf16(
                    af[mr], bf[nc], acc[mr][nc], 0, 0, 0);
        asm volatile("s_waitcnt vmcnt(0)" ::: "memory");
        __syncthreads();
        cur ^= 1;
    }

    const int orow = (lane >> 4) * 4;
    const int ocol = lane & 15;

    if (nkz > 1) {
        float* Of = (float*)Out + (size_t)z * M * N;
        #pragma unroll
        for (int mr = 0; mr < FM; ++mr)
            #pragma unroll
            for (int nc = 0; nc < FN; ++nc)
                #pragma unroll
                for (int j = 0; j < 4; ++j) {
                    int gm = m0 + wr + mr * 16 + orow + j;
                    int gn = n0 + wc + nc * 16 + ocol;
                    Of[(size_t)gm * N + gn] = acc[mr][nc][j];
                }
        return;
    }

    float mcol[FN], bcol[FN];
    #pragma unroll
    for (int nc = 0; nc < FN; ++nc) {
        int gn = n0 + wc + nc * 16 + ocol;
        mcol[nc] = (maskMode == 0) ? 1.0f
                 : (maskMode == 1) ? mask[gn]
                                   : (mask[gn] > 0.8f ? 1.0f : 0.0f);
        bcol[nc] = (biasMode == 2) ? bias[gn] : 0.0f;
    }
    ushort* Obf = (ushort*)Out + (size_t)br * outBrStride;
    float*  Of  = (float*)Out + (size_t)br * outBrStride;
    float lsum = 0.0f, lsq = 0.0f;
    #pragma unroll
    for (int mr = 0; mr < FM; ++mr) {
        #pragma unroll
        for (int j = 0; j < 4; ++j) {
            int gm = m0 + wr + mr * 16 + orow + j;
            float brow = (biasMode == 1) ? bias[gm] : 0.0f;
            #pragma unroll
            for (int nc = 0; nc < FN; ++nc) {
                int gn = n0 + wc + nc * 16 + ocol;
                float v = acc[mr][nc][j] * mcol[nc] + brow + bcol[nc];
                if (doRelu) v = fmaxf(v, 0.0f);
                if (outBf16) Obf[(size_t)gm * N + gn] = f2bf(v);
                else         Of[(size_t)gm * N + gn] = v;
                lsum += v; lsq = fmaf(v, v, lsq);
            }
        }
    }
    if (lnp) {
        __shared__ float redS[256], redQ[256];
        redS[tid] = lsum; redQ[tid] = lsq;
        __syncthreads();
        for (int s = 128; s > 0; s >>= 1) {
            if (tid < s) { redS[tid] += redS[tid + s]; redQ[tid] += redQ[tid + s]; }
            __syncthreads();
        }
        if (tid == 0) {
            int fb = blockIdx.y * gridDim.x + blockIdx.x;
            lnp[br * 512 + fb] = redS[0];
            lnp[br * 512 + 256 + fb] = redQ[0];
        }
    }
}

// sum 2 split-K partials * per-row softmax scale -> bf16 (z-batched)
__global__ __launch_bounds__(256) void reduce2row(
    const float* __restrict__ P4, const float* __restrict__ rowsump,
    ushort* __restrict__ O)
{
    const int br = blockIdx.y;
    const int tid = threadIdx.x;
    const int r0 = blockIdx.x * 2;
    __shared__ float invL[2];
    if (tid < 64) {
        int rw = tid >> 5, b = tid & 31;
        float s = rowsump[(size_t)br * 131072 + (size_t)b * 4096 + r0 + rw];
        #pragma unroll
        for (int m = 1; m < 32; m <<= 1) s += __shfl_xor(s, m, 64);
        if (b == 0) invL[rw] = 1.0f / s;
    }
    __syncthreads();
    int i = (blockIdx.x * 256 + tid) * 4;
    float sc = invL[(i >> 9) & 1];
    float4 a = *(const float4*)&P4[(size_t)(br * 2 + 0) * SZO + i];
    float4 b = *(const float4*)&P4[(size_t)(br * 2 + 1) * SZO + i];
    ushort4 o;
    o.x = f2bf((a.x + b.x) * sc);
    o.y = f2bf((a.y + b.y) * sc);
    o.z = f2bf((a.z + b.z) * sc);
    o.w = f2bf((a.w + b.w) * sc);
    *(ushort4*)&O[(size_t)br * SZO + i] = o;
}

// ---------------------------------------------------------------------------
// gate_write with folded ln_fin (identical tree order -> bitwise-same stats)
// ---------------------------------------------------------------------------
__global__ __launch_bounds__(256) void gate_write(
    const float* __restrict__ H2, const float* __restrict__ lnp,
    const float* __restrict__ gamma, const float* __restrict__ beta,
    const float* __restrict__ x, const float* __restrict__ y,
    const float* __restrict__ s_m, const float* __restrict__ q_m,
    float* __restrict__ out)
{
    const int br = blockIdx.y;
    const int tid = threadIdx.x;
    __shared__ double rs[256], rq[256];
    rs[tid] = (double)lnp[(size_t)br * 512 + tid];
    rq[tid] = (double)lnp[(size_t)br * 512 + 256 + tid];
    __syncthreads();
    for (int st = 128; st > 0; st >>= 1) {
        if (tid < st) { rs[tid] += rs[tid + st]; rq[tid] += rq[tid + st]; }
        __syncthreads();
    }
    double muD = rs[0] / (double)CN;
    double varD = rq[0] / (double)CN - muD * muD;
    float mu = (float)muD;
    float rstd = (float)(1.0 / sqrt(varD + 1e-5));

    size_t i = ((size_t)blockIdx.x * 256 + tid) * 4;
    int n = (int)(i & (N_DIM - 1));
    float4 h = *(const float4*)&H2[(size_t)br * CN + i];
    float4 g = *(const float4*)&gamma[i];
    float4 b = *(const float4*)&beta[i];
    const float* resid = br ? y : x;
    float4 r = *(const float4*)&resid[i];
    float vals[4] = { h.x, h.y, h.z, h.w };
    float gs[4] = { g.x, g.y, g.z, g.w };
    float bs[4] = { b.x, b.y, b.z, b.w };
    float rsv[4] = { r.x, r.y, r.z, r.w };
    float os[4];
    #pragma unroll
    for (int j = 0; j < 4; ++j) {
        float mv = br ? ((q_m[n + j] > 0.8f) ? 1.0f : 0.0f) : s_m[n + j];
        float normed = (vals[j] - mu) * rstd * gs[j] + bs[j];
        os[j] = normed * mv + rsv[j] * (1.0f - mv);
    }
    float4 o; o.x = os[0]; o.y = os[1]; o.z = os[2]; o.w = os[3];
    *(float4*)&out[(size_t)br * CN + i] = o;
}

// ---------------------------------------------------------------------------
extern "C" void kernel_launch(void* const* d_in, const int* in_sizes, int n_in,
                              void* d_out, int out_size, void* d_ws, size_t ws_size,
                              hipStream_t stream)
{
    const float* x     = (const float*)d_in[0];
    const float* y     = (const float*)d_in[1];
    const float* s_m   = (const float*)d_in[2];
    const float* q_m   = (const float*)d_in[3];
    const float* Wq    = (const float*)d_in[4];
    const float* bq    = (const float*)d_in[5];
    const float* Wk    = (const float*)d_in[6];
    const float* bk    = (const float*)d_in[7];
    const float* Wv    = (const float*)d_in[8];
    const float* bv    = (const float*)d_in[9];
    const float* W1    = (const float*)d_in[10];
    const float* b1    = (const float*)d_in[11];
    const float* W2    = (const float*)d_in[12];
    const float* b2    = (const float*)d_in[13];
    const float* gamma = (const float*)d_in[14];
    const float* beta  = (const float*)d_in[15];
    float* out = (float*)d_out;

    // ---- workspace layout (same as round 5/6) ----
    float* ws = (float*)d_ws;
    float*  R1    = ws;                         // 8,388,608 f
    float*  PX    = R1;                         // [2][2][128][4096]
    float*  P4    = R1;                         // [4][4096][512] split-K partials
    ushort* QF0   = (ushort*)(R1 + 4194304);
    ushort* KF0   = QF0 + 786432;
    ushort* QF1   = KF0 + 786432;
    ushort* KF1   = QF1 + 786432;
    float*  SMALL = R1 + 8388608;
    float*  PART  = SMALL;                      // [2][3072]
    float*  RMAXP = PART + 6144;                // [2][131072]
    float*  RSUMP = RMAXP + 262144;             // [2][131072]
    float*  LNP   = RSUMP + 262144;             // [2][512]
    float*  STATS = LNP + 1024;                 // 64 (unused)
    ushort* Wvb   = (ushort*)(STATS + 64);
    ushort* W1b   = Wvb + 262144;
    ushort* W2b   = W1b + 262144;
    ushort* Vb    = W2b + 262144;               // [2][512][4096]
    ushort* R2    = Vb + 4194304;
    ushort* xbT   = R2;                         // [4096][512] (dead after V-proj)
    ushort* ybT   = R2 + 2097152;
    ushort* Pe    = R2;                         // [2][4096][4096]
    ushort* O1T   = R2;                         // [2][4096][512] (Pe dead)
    ushort* H1T   = R2 + 4194304;               // [2][4096][512]
    float*  H2    = (float*)(R2 + 8388608);     // [2][512][4096] f32

    // 1. setup: tconv + weight cvt + Q/K raw proj (one launch)
    setup_all<<<2048, 256, 0, stream>>>(
        x, y, xbT, ybT, Wv, W1, W2, Wvb, W1b, W2b, Wq, Wk, PX);

    // 2. Q/K finish: reduce partials, mask/bias/scale, bf16x3 fragment layout
    qkfinish<<<256, 256, 0, stream>>>(PX, s_m, q_m, bq, bk, QF0, KF0, QF1, KF1);

    // 3. V-proj (256 blocks) backfilled under scores pass 1 (2048 blocks)
    vproj_p1<<<2304, 256, 0, stream>>>(
        Wvb, xbT, ybT, bv, q_m, Vb, QF0, KF0, QF1, KF1, PART, RMAXP);

    // 4. scores pass 2 (folded stats + row_fin)
    scores_pass2<<<dim3(32, 32, 2), 256, 0, stream>>>(
        QF0, KF0, QF1, KF1, PART, RMAXP, Pe, RSUMP);

    // 5. O1T = Pe . Vb^T (split-K x2, 128x128, swapped axes for L2 locality)
    mfma_g<128, 128><<<dim3(32, 4, 4), 256, 0, stream>>>(
        Pe, Pe + NN, Vb, Vb + CN, P4, 0,
        4096, 512, 4096, 2048, 2, 1, nullptr, 0, nullptr, 0, nullptr, 0, 0, 0, nullptr);

    // 6. split-K reduce + softmax normalize (folded rsum_fin)
    reduce2row<<<dim3(2048, 2), 256, 0, stream>>>(P4, RSUMP, O1T);

    // 7. MLP1: H1T = relu(O1T . W1^T + b1)
    mfma_g<128, 64><<<dim3(32, 8, 2), 256, 0, stream>>>(
        O1T, O1T + SZO, W1b, W1b, H1T, (size_t)SZO,
        4096, 512, 512, 512, 1, 1, b1, 2, nullptr, 0, nullptr, 0, 1, 1, nullptr);

    // 8. MLP2: H2 = W2 . H1T^T + b2 -> f32, fused LN partials
    mfma_g<64, 128><<<dim3(32, 8, 2), 256, 0, stream>>>(
        W2b, W2b, H1T, H1T + SZO, H2, (size_t)CN,
        512, 4096, 512, 512, 1, 0, b2, 1, nullptr, 0, nullptr, 0, 0, 0, LNP);

    // 9. gate + folded LayerNorm finalize
    gate_write<<<dim3(2048, 2), 256, 0, stream>>>(
        H2, LNP, gamma, beta, x, y, s_m, q_m, out);
}

// Round 8
// 258.401 us; speedup vs baseline: 1.1726x; 1.1726x over previous
//
#include <hip/hip_runtime.h>
#include <math.h>

#define C_DIM 512
#define N_DIM 4096
#define CN (C_DIM * N_DIM)
#define SZO (N_DIM * C_DIM)          // 2,097,152 (pixel x channel)
#define NN ((size_t)N_DIM * N_DIM)
#define NN_TOT ((long long)N_DIM * N_DIM)

typedef __attribute__((ext_vector_type(4))) float f32x4;
typedef __attribute__((ext_vector_type(8))) short short8;

__device__ __forceinline__ ushort f2bf(float f) {
    unsigned u = __float_as_uint(f);
    unsigned r = u + 0x7FFFu + ((u >> 16) & 1u);
    return (ushort)(r >> 16);
}
__device__ __forceinline__ float bf2f(ushort h) {
    return __uint_as_float((unsigned)h << 16);
}

__device__ __forceinline__ void gload16(const void* g, void* l) {
    __builtin_amdgcn_global_load_lds(
        (const __attribute__((address_space(1))) void*)g,
        (__attribute__((address_space(3))) void*)l, 16, 0, 0);
}

// ---------------------------------------------------------------------------
// setup_all: one launch, three independent roles.
//  id <  1024 : tconv  — x/y f32 [512][4096] -> xbT/ybT bf16 [4096][512]
//  id <  1792 : cvtw3  — Wv/W1/W2 f32 -> bf16
//  id <  2048 : qkraw2 — Q&K proj raw f32 split-K x2, PX[kz][src][128][4096]
// ---------------------------------------------------------------------------
__global__ __launch_bounds__(256) void setup_all(
    const float* __restrict__ x, const float* __restrict__ y,
    ushort* __restrict__ xbT, ushort* __restrict__ ybT,
    const float* __restrict__ Wv, const float* __restrict__ W1,
    const float* __restrict__ W2, ushort* __restrict__ Wvb,
    ushort* __restrict__ W1b, ushort* __restrict__ W2b,
    const float* __restrict__ Wq, const float* __restrict__ Wk,
    float* __restrict__ PX)
{
    __shared__ float t[64][65];
    __shared__ float Asw[16][130];
    __shared__ float Bsx[16][65];
    const int id = blockIdx.x;
    const int tid = threadIdx.x;

    if (id < 1024) {            // ---- tconv ----
        const int bx = id & 63, by = (id >> 6) & 7, bz = id >> 9;
        const float* X = bz ? y : x;
        ushort* XT = bz ? ybT : xbT;
        const int c0 = bx * 64, r0 = by * 64;
        const int ty = tid >> 4, tx = tid & 15;
        #pragma unroll
        for (int i = 0; i < 4; ++i) {
            int r = ty + i * 16;
            float4 v = *(const float4*)&X[(size_t)(r0 + r) * N_DIM + c0 + tx * 4];
            t[r][tx * 4 + 0] = v.x; t[r][tx * 4 + 1] = v.y;
            t[r][tx * 4 + 2] = v.z; t[r][tx * 4 + 3] = v.w;
        }
        __syncthreads();
        #pragma unroll
        for (int i = 0; i < 4; ++i) {
            int nn = ty + i * 16;
            ushort4 o;
            o.x = f2bf(t[tx * 4 + 0][nn]); o.y = f2bf(t[tx * 4 + 1][nn]);
            o.z = f2bf(t[tx * 4 + 2][nn]); o.w = f2bf(t[tx * 4 + 3][nn]);
            *(ushort4*)&XT[(size_t)(c0 + nn) * C_DIM + r0 + tx * 4] = o;
        }
        return;
    }
    if (id < 1792) {            // ---- cvtw3 ----
        const int i2 = id - 1024;
        const int bx = i2 & 255, by = i2 >> 8;
        const float* in  = (by == 0) ? Wv : (by == 1) ? W1 : W2;
        ushort*      out = (by == 0) ? Wvb : (by == 1) ? W1b : W2b;
        int i = (bx * 256 + tid) * 4;
        float4 v = *(const float4*)&in[i];
        ushort4 o = { f2bf(v.x), f2bf(v.y), f2bf(v.z), f2bf(v.w) };
        *(ushort4*)&out[i] = o;
        return;
    }
    // ---- qkraw2 ----
    {
        const int i3 = id - 1792;
        const int ntile = i3 & 63;
        const int srcT  = (i3 >> 6) & 1;
        const int kz    = i3 >> 7;
        const float* X = srcT ? y : x;
        const int n0 = ntile * 64;
        const int ty = tid >> 4, tx = tid & 15;
        float accQ[4][4] = {}, accK[4][4] = {};
        const int kbase = kz * 256;

        for (int k0 = kbase; k0 < kbase + 256; k0 += 16) {
            #pragma unroll
            for (int i = 0; i < 2; ++i) {
                int wi = tid + i * 256;       // 0..511
                int mm = wi >> 2;             // 0..127
                int kq = (wi & 3) * 4;
                const float* Wp = (mm < 64) ? &Wq[(size_t)mm * 512]
                                            : &Wk[(size_t)(mm - 64) * 512];
                float4 w4 = *(const float4*)&Wp[k0 + kq];
                Asw[kq + 0][mm] = w4.x; Asw[kq + 1][mm] = w4.y;
                Asw[kq + 2][mm] = w4.z; Asw[kq + 3][mm] = w4.w;
            }
            {
                int kk = tid >> 4, nq = (tid & 15) * 4;
                *(float4*)&Bsx[kk][nq] = *(const float4*)&X[(size_t)(k0 + kk) * N_DIM + n0 + nq];
            }
            __syncthreads();
            #pragma unroll
            for (int kk = 0; kk < 16; ++kk) {
                float aq[4], ak[4], b[4];
                #pragma unroll
                for (int r = 0; r < 4; ++r) { aq[r] = Asw[kk][ty * 4 + r]; ak[r] = Asw[kk][64 + ty * 4 + r]; }
                #pragma unroll
                for (int c = 0; c < 4; ++c) b[c] = Bsx[kk][tx * 4 + c];
                #pragma unroll
                for (int r = 0; r < 4; ++r)
                    #pragma unroll
                    for (int c = 0; c < 4; ++c) {
                        accQ[r][c] = fmaf(aq[r], b[c], accQ[r][c]);
                        accK[r][c] = fmaf(ak[r], b[c], accK[r][c]);
                    }
            }
            __syncthreads();
        }
        float* dst = PX + ((size_t)(kz * 2 + srcT) * 128) * N_DIM;
        #pragma unroll
        for (int r = 0; r < 4; ++r) {
            float4 oq = make_float4(accQ[r][0], accQ[r][1], accQ[r][2], accQ[r][3]);
            *(float4*)&dst[(size_t)(ty * 4 + r) * N_DIM + n0 + tx * 4] = oq;
            float4 ok = make_float4(accK[r][0], accK[r][1], accK[r][2], accK[r][3]);
            *(float4*)&dst[(size_t)(64 + ty * 4 + r) * N_DIM + n0 + tx * 4] = ok;
        }
    }
}

// ---------------------------------------------------------------------------
// Reduce PX partials, apply mask/bias/scale per use-case, split hi/lo bf16x3,
// write QF0/KF0/QF1/KF1 in score-fragment layout [256][6][64][8].
// ---------------------------------------------------------------------------
__global__ __launch_bounds__(256) void qkfinish(
    const float* __restrict__ PX,
    const float* __restrict__ s_m, const float* __restrict__ q_m,
    const float* __restrict__ bq, const float* __restrict__ bk,
    ushort* __restrict__ QF0, ushort* __restrict__ KF0,
    ushort* __restrict__ QF1, ushort* __restrict__ KF1)
{
    int gid = blockIdx.x * 256 + threadIdx.x;
    int lane = gid & 63;
    int rest = gid >> 6;
    int blk = rest & 255;
    int tensor = rest >> 8;       // 0..3
    int fr = lane & 15, quad = lane >> 4;
    int n = blk * 16 + fr;

    int srcT, rowbase, isQ;
    const float* bias;
    ushort* dst;
    float mv, scale;
    if (tensor == 0)      { srcT = 0; rowbase = 0;  isQ = 1; bias = bq; dst = QF0; scale = 0.125f; mv = s_m[n]; }
    else if (tensor == 1) { srcT = 1; rowbase = 64; isQ = 0; bias = bk; dst = KF0; scale = 1.0f;   mv = (q_m[n] > 0.8f) ? 1.0f : 0.0f; }
    else if (tensor == 2) { srcT = 1; rowbase = 0;  isQ = 1; bias = bq; dst = QF1; scale = 0.125f; mv = (q_m[n] > 0.8f) ? 1.0f : 0.0f; }
    else                  { srcT = 0; rowbase = 64; isQ = 0; bias = bk; dst = KF1; scale = 1.0f;   mv = 1.0f; }

    ushort hi0[8], lo0[8], hi1[8], lo1[8];
    #pragma unroll
    for (int j = 0; j < 8; ++j) {
        int d0 = quad * 8 + j, d1 = 32 + d0;
        float v0 = 0.0f, v1 = 0.0f;
        #pragma unroll
        for (int kz = 0; kz < 2; ++kz) {
            size_t base = ((size_t)(kz * 2 + srcT) * 128 + rowbase);
            v0 += PX[(base + d0) * N_DIM + n];
            v1 += PX[(base + d1) * N_DIM + n];
        }
        v0 = (v0 * mv + bias[d0]) * scale;
        v1 = (v1 * mv + bias[d1]) * scale;
        hi0[j] = f2bf(v0); lo0[j] = f2bf(v0 - bf2f(hi0[j]));
        hi1[j] = f2bf(v1); lo1[j] = f2bf(v1 - bf2f(hi1[j]));
    }
    auto wr8 = [&](int kstep, const ushort* v) {
        size_t base = ((size_t)(blk * 6 + kstep) * 64 + lane) * 8;
        *(ushort4*)&dst[base]     = *(const ushort4*)&v[0];
        *(ushort4*)&dst[base + 4] = *(const ushort4*)&v[4];
    };
    wr8(0, hi0); wr8(1, hi1);
    if (isQ) { wr8(2, hi0); wr8(3, hi1); wr8(4, lo0); wr8(5, lo1); }
    else     { wr8(2, lo0); wr8(3, lo1); wr8(4, hi0); wr8(5, hi1); }
}

// shared MFMA core for the two score passes (identical arithmetic order!)
__device__ __forceinline__ void scores_mfma(
    const ushort* __restrict__ QF, const ushort* __restrict__ KF,
    int m0, int n0, int wr, int wc, int lane, f32x4 acc[4][4])
{
    const int blkA0 = (m0 + wr) >> 4;
    const int blkB0 = (n0 + wc) >> 4;
    #pragma unroll
    for (int s = 0; s < 6; ++s) {
        short8 af[4], bf[4];
        #pragma unroll
        for (int mr = 0; mr < 4; ++mr)
            af[mr] = *(const short8*)&QF[((size_t)((blkA0 + mr) * 6 + s) * 64 + lane) * 8];
        #pragma unroll
        for (int nc = 0; nc < 4; ++nc)
            bf[nc] = *(const short8*)&KF[((size_t)((blkB0 + nc) * 6 + s) * 64 + lane) * 8];
        #pragma unroll
        for (int mr = 0; mr < 4; ++mr)
            #pragma unroll
            for (int nc = 0; nc < 4; ++nc)
                acc[mr][nc] = __builtin_amdgcn_mfma_f32_16x16x32_bf16(
                    af[mr], bf[nc], acc[mr][nc], 0, 0, 0);
    }
}

// ---------------------------------------------------------------------------
// vproj_p1: one launch, two independent roles.
//  id < 256  : V projection, bf16 MFMA NT <128,128>, both branches
//  id >= 256 : scores pass 1 (global max/min/sum partials + per-row max)
// ---------------------------------------------------------------------------
__global__ __launch_bounds__(256) void vproj_p1(
    const ushort* __restrict__ Wvb,
    const ushort* __restrict__ xbT, const ushort* __restrict__ ybT,
    const float* __restrict__ bv, const float* __restrict__ q_m,
    ushort* __restrict__ Vb,
    const ushort* __restrict__ QF0, const ushort* __restrict__ KF0,
    const ushort* __restrict__ QF1, const ushort* __restrict__ KF1,
    float* __restrict__ part, float* __restrict__ rowmaxp)
{
    __shared__ ushort As[2][128 * 32];
    __shared__ ushort Bs[2][128 * 32];
    __shared__ float wrm[2][128];
    __shared__ float red[256];
    const int id = blockIdx.x;
    const int tid = threadIdx.x;
    const int lane = tid & 63;
    const int wid  = tid >> 6;

    if (id < 256) {
        // ================= V-proj path: Vb[br] = Wv . B + bv ==============
        const int bxn = id & 31;
        const int bym = (id >> 5) & 3;
        const int br  = id >> 7;
        const ushort* A = Wvb;
        const ushort* B = br ? xbT : ybT;
        const int m0 = bym * 128, n0 = bxn * 128;
        const int wr = (wid >> 1) * 64, wc = (wid & 1) * 64;
        const int lrow = lane >> 2;
        const int kbl  = lane & 3;
        const int K = 512;

        auto stage = [&](int buf, int t) {
            #pragma unroll
            for (int c = wid; c < 16; c += 4) {
                if (c < 8) {
                    int r = c * 16 + lrow;
                    int kb = kbl ^ ((r >> 1) & 3);
                    gload16(A + (size_t)(m0 + r) * K + t * 32 + kb * 8, &As[buf][c * 512]);
                } else {
                    int cb = c - 8;
                    int r = cb * 16 + lrow;
                    int kb = kbl ^ ((r >> 1) & 3);
                    gload16(B + (size_t)(n0 + r) * K + t * 32 + kb * 8, &Bs[buf][cb * 512]);
                }
            }
        };

        f32x4 acc[4][4] = {};
        const int fr = lane & 15;
        const int kq = lane >> 4;
        stage(0, 0);
        asm volatile("s_waitcnt vmcnt(0)" ::: "memory");
        __syncthreads();
        int cur = 0;
        for (int t = 0; t < 16; ++t) {
            if (t + 1 < 16) stage(cur ^ 1, t + 1);
            short8 af[4], bf[4];
            #pragma unroll
            for (int mr = 0; mr < 4; ++mr) {
                int rA = wr + mr * 16 + fr;
                af[mr] = *(const short8*)&As[cur][rA * 32 + (kq ^ ((rA >> 1) & 3)) * 8];
            }
            #pragma unroll
            for (int nc = 0; nc < 4; ++nc) {
                int rB = wc + nc * 16 + fr;
                bf[nc] = *(const short8*)&Bs[cur][rB * 32 + (kq ^ ((rB >> 1) & 3)) * 8];
            }
            #pragma unroll
            for (int mr = 0; mr < 4; ++mr)
                #pragma unroll
                for (int nc = 0; nc < 4; ++nc)
                    acc[mr][nc] = __builtin_amdgcn_mfma_f32_16x16x32_bf16(
                        af[mr], bf[nc], acc[mr][nc], 0, 0, 0);
            asm volatile("s_waitcnt vmcnt(0)" ::: "memory");
            __syncthreads();
            cur ^= 1;
        }
        const int orow = (lane >> 4) * 4;
        const int ocol = lane & 15;
        float mcol[4];
        #pragma unroll
        for (int nc = 0; nc < 4; ++nc) {
            int gn = n0 + wc + nc * 16 + ocol;
            mcol[nc] = br ? 1.0f : ((q_m[gn] > 0.8f) ? 1.0f : 0.0f);
        }
        ushort* Obf = Vb + (size_t)br * CN;
        #pragma unroll
        for (int mr = 0; mr < 4; ++mr)
            #pragma unroll
            for (int j = 0; j < 4; ++j) {
                int gm = m0 + wr + mr * 16 + orow + j;
                float brow = bv[gm];
                #pragma unroll
                for (int nc = 0; nc < 4; ++nc) {
                    int gn = n0 + wc + nc * 16 + ocol;
                    float v = acc[mr][nc][j] * mcol[nc] + brow;
                    Obf[(size_t)gm * N_DIM + gn] = f2bf(v);
                }
            }
        return;
    }

    // ================= scores pass 1 path =================================
    {
        const int p = id - 256;
        const int bxn = p & 31;
        const int bym = (p >> 5) & 31;
        const int br  = p >> 10;
        const ushort* QF = br ? QF1 : QF0;
        const ushort* KF = br ? KF1 : KF0;
        float* pt = part + (size_t)br * 3072;
        float* rmp = rowmaxp + (size_t)br * 131072;

        const int m0 = bym * 128, n0 = bxn * 128;
        const int wr = (wid >> 1) * 64, wc = (wid & 1) * 64;
        f32x4 acc[4][4] = {};
        scores_mfma(QF, KF, m0, n0, wr, wc, lane, acc);

        float lmax = -3.4e38f, lmin = 3.4e38f, lsum = 0.0f;
        float rmx[4][4];
        #pragma unroll
        for (int mr = 0; mr < 4; ++mr)
            #pragma unroll
            for (int j = 0; j < 4; ++j) rmx[mr][j] = -3.4e38f;
        #pragma unroll
        for (int mr = 0; mr < 4; ++mr)
            #pragma unroll
            for (int nc = 0; nc < 4; ++nc)
                #pragma unroll
                for (int j = 0; j < 4; ++j) {
                    float v = acc[mr][nc][j];
                    lsum += v; lmax = fmaxf(lmax, v); lmin = fminf(lmin, v);
                    rmx[mr][j] = fmaxf(rmx[mr][j], v);
                }
        #pragma unroll
        for (int m = 1; m < 16; m <<= 1)
            #pragma unroll
            for (int mr = 0; mr < 4; ++mr)
                #pragma unroll
                for (int j = 0; j < 4; ++j)
                    rmx[mr][j] = fmaxf(rmx[mr][j], __shfl_xor(rmx[mr][j], m, 64));

        const int orow = (lane >> 4) * 4;
        if ((lane & 15) == 0) {
            #pragma unroll
            for (int mr = 0; mr < 4; ++mr)
                #pragma unroll
                for (int j = 0; j < 4; ++j)
                    wrm[wid & 1][wr + mr * 16 + orow + j] = rmx[mr][j];
        }
        __syncthreads();
        if (tid < 128) {
            float v = fmaxf(wrm[0][tid], wrm[1][tid]);
            rmp[(size_t)bxn * 4096 + m0 + tid] = v;
        }

        const int bid = bym * 32 + bxn;
        __syncthreads();
        red[tid] = lmax; __syncthreads();
        for (int s = 128; s > 0; s >>= 1) { if (tid < s) red[tid] = fmaxf(red[tid], red[tid + s]); __syncthreads(); }
        if (tid == 0) pt[bid] = red[0];
        __syncthreads();
        red[tid] = lmin; __syncthreads();
        for (int s = 128; s > 0; s >>= 1) { if (tid < s) red[tid] = fminf(red[tid], red[tid + s]); __syncthreads(); }
        if (tid == 0) pt[1024 + bid] = red[0];
        __syncthreads();
        red[tid] = lsum; __syncthreads();
        for (int s = 128; s > 0; s >>= 1) { if (tid < s) red[tid] += red[tid + s]; __syncthreads(); }
        if (tid == 0) pt[2048 + bid] = red[0];
    }
}

// thr per branch: branch0 max-based, branch1 min-based (separate tiny kernel —
// folding this into pass2 caused a VGPR cliff, r7 post-mortem)
__global__ __launch_bounds__(256) void stats_fin2(
    const float* __restrict__ part, float* __restrict__ stats)
{
    const int br = blockIdx.x;
    part += (size_t)br * 3072;
    __shared__ float rmax[256], rmin[256];
    __shared__ double rsum[256];
    int tid = threadIdx.x;
    float m1 = -3.4e38f, m2 = 3.4e38f; double s = 0.0;
    for (int i = tid; i < 1024; i += 256) {
        m1 = fmaxf(m1, part[i]);
        m2 = fminf(m2, part[1024 + i]);
        s += (double)part[2048 + i];
    }
    rmax[tid] = m1; rmin[tid] = m2; rsum[tid] = s;
    __syncthreads();
    for (int st = 128; st > 0; st >>= 1) {
        if (tid < st) {
            rmax[tid] = fmaxf(rmax[tid], rmax[tid + st]);
            rmin[tid] = fminf(rmin[tid], rmin[tid + st]);
            rsum[tid] += rsum[tid + st];
        }
        __syncthreads();
    }
    if (tid == 0) {
        float stat = (br == 0) ? rmax[0] : rmin[0];
        float mean = (float)(rsum[0] / (double)NN_TOT);
        stats[br] = 0.5f * (stat + mean);
    }
}

// ---------------------------------------------------------------------------
// pass 2 (z-batched): folded row_fin only (round-5 proven form); recompute
// scores, write e = exp(s-m) bf16 + rowsum partials.
// ---------------------------------------------------------------------------
__global__ __launch_bounds__(256) void scores_pass2(
    const ushort* __restrict__ QF0, const ushort* __restrict__ KF0,
    const ushort* __restrict__ QF1, const ushort* __restrict__ KF1,
    const float* __restrict__ stats, const float* __restrict__ rowmaxp,
    ushort* __restrict__ Pe, float* __restrict__ rowsump)
{
    const int br = blockIdx.z;
    const ushort* QF = br ? QF1 : QF0;
    const ushort* KF = br ? KF1 : KF0;
    ushort* P = Pe + (size_t)br * NN;
    rowsump += (size_t)br * 131072;
    rowmaxp += (size_t)br * 131072;

    const int tid = threadIdx.x;
    const int lane = tid & 63, wid = tid >> 6;
    const int m0 = blockIdx.y * 128, n0 = blockIdx.x * 128;
    const int wr = (wid >> 1) * 64, wc = (wid & 1) * 64;
    const float thr = stats[br];

    // folded row_fin: rowm for this block's 128 rows
    __shared__ float rowmL[128];
    if (tid < 128) {
        int r = m0 + tid;
        float m = -3.4e38f;
        #pragma unroll 8
        for (int b = 0; b < 32; ++b)
            m = fmaxf(m, rowmaxp[(size_t)b * 4096 + r]);
        rowmL[tid] = (m >= thr) ? m : -1e30f;
    }
    __syncthreads();

    f32x4 acc[4][4] = {};
    scores_mfma(QF, KF, m0, n0, wr, wc, lane, acc);

    const int orow = (lane >> 4) * 4;
    const int ocol = lane & 15;
    float rm[4][4], rs[4][4];
    #pragma unroll
    for (int mr = 0; mr < 4; ++mr)
        #pragma unroll
        for (int j = 0; j < 4; ++j) {
            rm[mr][j] = rowmL[wr + mr * 16 + orow + j];
            rs[mr][j] = 0.0f;
        }
    #pragma unroll
    for (int mr = 0; mr < 4; ++mr)
        #pragma unroll
        for (int nc = 0; nc < 4; ++nc)
            #pragma unroll
            for (int j = 0; j < 4; ++j) {
                float s = acc[mr][nc][j];
                float m = rm[mr][j];
                float e = (s < thr) ? 0.0f : __expf(s - m);
                if (m < -1e29f) e = 1.0f;          // fully-masked row -> uniform
                ushort h = f2bf(e);
                rs[mr][j] += bf2f(h);
                P[(size_t)(m0 + wr + mr * 16 + orow + j) * N_DIM
                  + n0 + wc + nc * 16 + ocol] = h;
            }
    #pragma unroll
    for (int m = 1; m < 16; m <<= 1)
        #pragma unroll
        for (int mr = 0; mr < 4; ++mr)
            #pragma unroll
            for (int j = 0; j < 4; ++j)
                rs[mr][j] += __shfl_xor(rs[mr][j], m, 64);

    __shared__ float wrs[2][128];
    if ((lane & 15) == 0) {
        #pragma unroll
        for (int mr = 0; mr < 4; ++mr)
            #pragma unroll
            for (int j = 0; j < 4; ++j)
                wrs[wid & 1][wr + mr * 16 + orow + j] = rs[mr][j];
    }
    __syncthreads();
    if (tid < 128)
        rowsump[(size_t)blockIdx.x * 4096 + m0 + tid] =
            wrs[0][tid] + wrs[1][tid];
}

// ---------------------------------------------------------------------------
// Generic bf16 MFMA NT GEMM (round-5 proven).
// ---------------------------------------------------------------------------
template<int BM, int BN>
__global__ __launch_bounds__(256) void mfma_g(
    const ushort* __restrict__ A0, const ushort* __restrict__ A1,
    const ushort* __restrict__ B0, const ushort* __restrict__ B1,
    void* __restrict__ Out, size_t outBrStride,
    int M, int N, int K, int kLen, int nkz, int swapxy,
    const float* __restrict__ bias, int biasMode,
    const float* __restrict__ mask0, int mm0,
    const float* __restrict__ mask1, int mm1,
    int doRelu, int outBf16, float* __restrict__ lnp)
{
    constexpr int WAVES_M = BM / 64;
    constexpr int WAVES_N = 4 / WAVES_M;
    constexpr int WN = BN / WAVES_N;
    constexpr int FM = 4;
    constexpr int FN = WN / 16;
    constexpr int NCHUNK = (BM + BN) / 16;

    __shared__ ushort As[2][BM * 32];
    __shared__ ushort Bs[2][BN * 32];
    const int tid  = threadIdx.x;
    const int lane = tid & 63;
    const int wid  = tid >> 6;
    const int z  = blockIdx.z;
    const int br = z / nkz;
    const int kz = z % nkz;
    const ushort* A = br ? A1 : A0;
    const ushort* B = br ? B1 : B0;
    const float* mask = br ? mask1 : mask0;
    const int maskMode = br ? mm1 : mm0;

    const int bxm = swapxy ? blockIdx.x : blockIdx.y;
    const int bxn = swapxy ? blockIdx.y : blockIdx.x;
    const int m0 = bxm * BM, n0 = bxn * BN;
    const int wm = wid / WAVES_N, wn = wid % WAVES_N;
    const int wr = wm * 64, wc = wn * WN;
    const int kOff = kz * kLen;
    const int lrow = lane >> 2;
    const int kbl  = lane & 3;

    auto stage = [&](int buf, int t) {
        #pragma unroll
        for (int c = wid; c < NCHUNK; c += 4) {
            if (c < BM / 16) {
                int r = c * 16 + lrow;
                int kb = kbl ^ ((r >> 1) & 3);
                gload16(A + (size_t)(m0 + r) * K + kOff + t * 32 + kb * 8,
                        &As[buf][c * 512]);
            } else {
                int cb = c - BM / 16;
                int r = cb * 16 + lrow;
                int kb = kbl ^ ((r >> 1) & 3);
                gload16(B + (size_t)(n0 + r) * K + kOff + t * 32 + kb * 8,
                        &Bs[buf][cb * 512]);
            }
        }
    };

    f32x4 acc[FM][FN] = {};
    const int fr = lane & 15;
    const int kq = lane >> 4;
    const int nt = kLen / 32;

    stage(0, 0);
    asm volatile("s_waitcnt vmcnt(0)" ::: "memory");
    __syncthreads();
    int cur = 0;
    for (int t = 0; t < nt; ++t) {
        if (t + 1 < nt) stage(cur ^ 1, t + 1);
        short8 af[FM], bf[FN];
        #pragma unroll
        for (int mr = 0; mr < FM; ++mr) {
            int rA = wr + mr * 16 + fr;
            af[mr] = *(const short8*)&As[cur][rA * 32 + (kq ^ ((rA >> 1) & 3)) * 8];
        }
        #pragma unroll
        for (int nc = 0; nc < FN; ++nc) {
            int rB = wc + nc * 16 + fr;
            bf[nc] = *(const short8*)&Bs[cur][rB * 32 + (kq ^ ((rB >> 1) & 3)) * 8];
        }
        #pragma unroll
        for (int mr = 0; mr < FM; ++mr)
            #pragma unroll
            for (int nc = 0; nc < FN; ++nc)
                acc[mr][nc] = __builtin_amdgcn_mfma_f32_16x16x32_bf16(
                    af[mr], bf[nc], acc[mr][nc], 0, 0, 0);
        asm volatile("s_waitcnt vmcnt(0)" ::: "memory");
        __syncthreads();
        cur ^= 1;
    }

    const int orow = (lane >> 4) * 4;
    const int ocol = lane & 15;

    if (nkz > 1) {
        float* Of = (float*)Out + (size_t)z * M * N;
        #pragma unroll
        for (int mr = 0; mr < FM; ++mr)
            #pragma unroll
            for (int nc = 0; nc < FN; ++nc)
                #pragma unroll
                for (int j = 0; j < 4; ++j) {
                    int gm = m0 + wr + mr * 16 + orow + j;
                    int gn = n0 + wc + nc * 16 + ocol;
                    Of[(size_t)gm * N + gn] = acc[mr][nc][j];
                }
        return;
    }

    float mcol[FN], bcol[FN];
    #pragma unroll
    for (int nc = 0; nc < FN; ++nc) {
        int gn = n0 + wc + nc * 16 + ocol;
        mcol[nc] = (maskMode == 0) ? 1.0f
                 : (maskMode == 1) ? mask[gn]
                                   : (mask[gn] > 0.8f ? 1.0f : 0.0f);
        bcol[nc] = (biasMode == 2) ? bias[gn] : 0.0f;
    }
    ushort* Obf = (ushort*)Out + (size_t)br * outBrStride;
    float*  Of  = (float*)Out + (size_t)br * outBrStride;
    float lsum = 0.0f, lsq = 0.0f;
    #pragma unroll
    for (int mr = 0; mr < FM; ++mr) {
        #pragma unroll
        for (int j = 0; j < 4; ++j) {
            int gm = m0 + wr + mr * 16 + orow + j;
            float brow = (biasMode == 1) ? bias[gm] : 0.0f;
            #pragma unroll
            for (int nc = 0; nc < FN; ++nc) {
                int gn = n0 + wc + nc * 16 + ocol;
                float v = acc[mr][nc][j] * mcol[nc] + brow + bcol[nc];
                if (doRelu) v = fmaxf(v, 0.0f);
                if (outBf16) Obf[(size_t)gm * N + gn] = f2bf(v);
                else         Of[(size_t)gm * N + gn] = v;
                lsum += v; lsq = fmaf(v, v, lsq);
            }
        }
    }
    if (lnp) {
        __shared__ float redS[256], redQ[256];
        redS[tid] = lsum; redQ[tid] = lsq;
        __syncthreads();
        for (int s = 128; s > 0; s >>= 1) {
            if (tid < s) { redS[tid] += redS[tid + s]; redQ[tid] += redQ[tid + s]; }
            __syncthreads();
        }
        if (tid == 0) {
            int fb = blockIdx.y * gridDim.x + blockIdx.x;
            lnp[br * 512 + fb] = redS[0];
            lnp[br * 512 + 256 + fb] = redQ[0];
        }
    }
}

// sum 2 split-K partials * per-row softmax scale -> bf16 (z-batched)
__global__ __launch_bounds__(256) void reduce2row(
    const float* __restrict__ P4, const float* __restrict__ rowsump,
    ushort* __restrict__ O)
{
    const int br = blockIdx.y;
    const int tid = threadIdx.x;
    const int r0 = blockIdx.x * 2;
    __shared__ float invL[2];
    if (tid < 64) {
        int rw = tid >> 5, b = tid & 31;
        float s = rowsump[(size_t)br * 131072 + (size_t)b * 4096 + r0 + rw];
        #pragma unroll
        for (int m = 1; m < 32; m <<= 1) s += __shfl_xor(s, m, 64);
        if (b == 0) invL[rw] = 1.0f / s;
    }
    __syncthreads();
    int i = (blockIdx.x * 256 + tid) * 4;
    float sc = invL[(i >> 9) & 1];
    float4 a = *(const float4*)&P4[(size_t)(br * 2 + 0) * SZO + i];
    float4 b = *(const float4*)&P4[(size_t)(br * 2 + 1) * SZO + i];
    ushort4 o;
    o.x = f2bf((a.x + b.x) * sc);
    o.y = f2bf((a.y + b.y) * sc);
    o.z = f2bf((a.z + b.z) * sc);
    o.w = f2bf((a.w + b.w) * sc);
    *(ushort4*)&O[(size_t)br * SZO + i] = o;
}

// ---------------------------------------------------------------------------
// gate_write with folded ln_fin (identical tree order -> bitwise-same stats)
// ---------------------------------------------------------------------------
__global__ __launch_bounds__(256) void gate_write(
    const float* __restrict__ H2, const float* __restrict__ lnp,
    const float* __restrict__ gamma, const float* __restrict__ beta,
    const float* __restrict__ x, const float* __restrict__ y,
    const float* __restrict__ s_m, const float* __restrict__ q_m,
    float* __restrict__ out)
{
    const int br = blockIdx.y;
    const int tid = threadIdx.x;
    __shared__ double rs[256], rq[256];
    rs[tid] = (double)lnp[(size_t)br * 512 + tid];
    rq[tid] = (double)lnp[(size_t)br * 512 + 256 + tid];
    __syncthreads();
    for (int st = 128; st > 0; st >>= 1) {
        if (tid < st) { rs[tid] += rs[tid + st]; rq[tid] += rq[tid + st]; }
        __syncthreads();
    }
    double muD = rs[0] / (double)CN;
    double varD = rq[0] / (double)CN - muD * muD;
    float mu = (float)muD;
    float rstd = (float)(1.0 / sqrt(varD + 1e-5));

    size_t i = ((size_t)blockIdx.x * 256 + tid) * 4;
    int n = (int)(i & (N_DIM - 1));
    float4 h = *(const float4*)&H2[(size_t)br * CN + i];
    float4 g = *(const float4*)&gamma[i];
    float4 b = *(const float4*)&beta[i];
    const float* resid = br ? y : x;
    float4 r = *(const float4*)&resid[i];
    float vals[4] = { h.x, h.y, h.z, h.w };
    float gs[4] = { g.x, g.y, g.z, g.w };
    float bs[4] = { b.x, b.y, b.z, b.w };
    float rsv[4] = { r.x, r.y, r.z, r.w };
    float os[4];
    #pragma unroll
    for (int j = 0; j < 4; ++j) {
        float mv = br ? ((q_m[n + j] > 0.8f) ? 1.0f : 0.0f) : s_m[n + j];
        float normed = (vals[j] - mu) * rstd * gs[j] + bs[j];
        os[j] = normed * mv + rsv[j] * (1.0f - mv);
    }
    float4 o; o.x = os[0]; o.y = os[1]; o.z = os[2]; o.w = os[3];
    *(float4*)&out[(size_t)br * CN + i] = o;
}

// ---------------------------------------------------------------------------
extern "C" void kernel_launch(void* const* d_in, const int* in_sizes, int n_in,
                              void* d_out, int out_size, void* d_ws, size_t ws_size,
                              hipStream_t stream)
{
    const float* x     = (const float*)d_in[0];
    const float* y     = (const float*)d_in[1];
    const float* s_m   = (const float*)d_in[2];
    const float* q_m   = (const float*)d_in[3];
    const float* Wq    = (const float*)d_in[4];
    const float* bq    = (const float*)d_in[5];
    const float* Wk    = (const float*)d_in[6];
    const float* bk    = (const float*)d_in[7];
    const float* Wv    = (const float*)d_in[8];
    const float* bv    = (const float*)d_in[9];
    const float* W1    = (const float*)d_in[10];
    const float* b1    = (const float*)d_in[11];
    const float* W2    = (const float*)d_in[12];
    const float* b2    = (const float*)d_in[13];
    const float* gamma = (const float*)d_in[14];
    const float* beta  = (const float*)d_in[15];
    float* out = (float*)d_out;

    // ---- workspace layout ----
    float* ws = (float*)d_ws;
    float*  R1    = ws;                         // 8,388,608 f
    float*  PX    = R1;                         // [2][2][128][4096]
    float*  P4    = R1;                         // [4][4096][512] split-K partials
    ushort* QF0   = (ushort*)(R1 + 4194304);
    ushort* KF0   = QF0 + 786432;
    ushort* QF1   = KF0 + 786432;
    ushort* KF1   = QF1 + 786432;
    float*  SMALL = R1 + 8388608;
    float*  PART  = SMALL;                      // [2][3072]
    float*  RMAXP = PART + 6144;                // [2][131072]
    float*  RSUMP = RMAXP + 262144;             // [2][131072]
    float*  LNP   = RSUMP + 262144;             // [2][512]
    float*  STATS = LNP + 1024;                 // 64
    ushort* Wvb   = (ushort*)(STATS + 64);
    ushort* W1b   = Wvb + 262144;
    ushort* W2b   = W1b + 262144;
    ushort* Vb    = W2b + 262144;               // [2][512][4096]
    ushort* R2    = Vb + 4194304;
    ushort* xbT   = R2;                         // [4096][512] (dead after V-proj)
    ushort* ybT   = R2 + 2097152;
    ushort* Pe    = R2;                         // [2][4096][4096]
    ushort* O1T   = R2;                         // [2][4096][512] (Pe dead)
    ushort* H1T   = R2 + 4194304;               // [2][4096][512]
    float*  H2    = (float*)(R2 + 8388608);     // [2][512][4096] f32

    // 1. setup: tconv + weight cvt + Q/K raw proj (one launch)
    setup_all<<<2048, 256, 0, stream>>>(
        x, y, xbT, ybT, Wv, W1, W2, Wvb, W1b, W2b, Wq, Wk, PX);

    // 2. Q/K finish: reduce partials, mask/bias/scale, bf16x3 fragment layout
    qkfinish<<<256, 256, 0, stream>>>(PX, s_m, q_m, bq, bk, QF0, KF0, QF1, KF1);

    // 3. V-proj (256 blocks) backfilled under scores pass 1 (2048 blocks)
    vproj_p1<<<2304, 256, 0, stream>>>(
        Wvb, xbT, ybT, bv, q_m, Vb, QF0, KF0, QF1, KF1, PART, RMAXP);

    // 4. threshold finalize (tiny separate kernel — see r7 post-mortem)
    stats_fin2<<<2, 256, 0, stream>>>(PART, STATS);

    // 5. scores pass 2 (folded row_fin only)
    scores_pass2<<<dim3(32, 32, 2), 256, 0, stream>>>(
        QF0, KF0, QF1, KF1, STATS, RMAXP, Pe, RSUMP);

    // 6. O1T = Pe . Vb^T (split-K x2, 128x128, swapped axes for L2 locality)
    mfma_g<128, 128><<<dim3(32, 4, 4), 256, 0, stream>>>(
        Pe, Pe + NN, Vb, Vb + CN, P4, 0,
        4096, 512, 4096, 2048, 2, 1, nullptr, 0, nullptr, 0, nullptr, 0, 0, 0, nullptr);

    // 7. split-K reduce + softmax normalize (folded rsum_fin)
    reduce2row<<<dim3(2048, 2), 256, 0, stream>>>(P4, RSUMP, O1T);

    // 8. MLP1: H1T = relu(O1T . W1^T + b1)
    mfma_g<128, 64><<<dim3(32, 8, 2), 256, 0, stream>>>(
        O1T, O1T + SZO, W1b, W1b, H1T, (size_t)SZO,
        4096, 512, 512, 512, 1, 1, b1, 2, nullptr, 0, nullptr, 0, 1, 1, nullptr);

    // 9. MLP2: H2 = W2 . H1T^T + b2 -> f32, fused LN partials
    mfma_g<64, 128><<<dim3(32, 8, 2), 256, 0, stream>>>(
        W2b, W2b, H1T, H1T + SZO, H2, (size_t)CN,
        512, 4096, 512, 512, 1, 0, b2, 1, nullptr, 0, nullptr, 0, 0, 0, LNP);

    // 10. gate + folded LayerNorm finalize
    gate_write<<<dim3(2048, 2), 256, 0, stream>>>(
        H2, LNP, gamma, beta, x, y, s_m, q_m, out);
}

// Round 9
// 230.115 us; speedup vs baseline: 1.3167x; 1.1229x over previous
//
#include <hip/hip_runtime.h>
#include <math.h>

#define C_DIM 512
#define N_DIM 4096
#define CN (C_DIM * N_DIM)
#define SZO (N_DIM * C_DIM)          // 2,097,152 (pixel x channel)
#define NN ((size_t)N_DIM * N_DIM)
#define NN_TOT ((long long)N_DIM * N_DIM)

typedef __attribute__((ext_vector_type(4))) float f32x4;
typedef __attribute__((ext_vector_type(8))) short short8;

__device__ __forceinline__ ushort f2bf(float f) {
    unsigned u = __float_as_uint(f);
    unsigned r = u + 0x7FFFu + ((u >> 16) & 1u);
    return (ushort)(r >> 16);
}
__device__ __forceinline__ float bf2f(ushort h) {
    return __uint_as_float((unsigned)h << 16);
}

__device__ __forceinline__ void gload16(const void* g, void* l) {
    __builtin_amdgcn_global_load_lds(
        (const __attribute__((address_space(1))) void*)g,
        (__attribute__((address_space(3))) void*)l, 16, 0, 0);
}

// ---------------------------------------------------------------------------
// setup2: one launch, three memory-bound roles (no f32 GEMM anymore).
//  id <  1024 : tconv hi+lo — x/y f32 [512][4096] -> x/ybT (hi) + x/ylT (lo)
//  id <  1792 : cvtw3 — Wv/W1/W2 f32 -> bf16
//  id <  1856 : cvtqk — Wq,Wk f32 -> WqkH/WqkL [128][512] bf16 hi/lo
// ---------------------------------------------------------------------------
__global__ __launch_bounds__(256) void setup2(
    const float* __restrict__ x, const float* __restrict__ y,
    ushort* __restrict__ xbT, ushort* __restrict__ xlT,
    ushort* __restrict__ ybT, ushort* __restrict__ ylT,
    const float* __restrict__ Wv, const float* __restrict__ W1,
    const float* __restrict__ W2, ushort* __restrict__ Wvb,
    ushort* __restrict__ W1b, ushort* __restrict__ W2b,
    const float* __restrict__ Wq, const float* __restrict__ Wk,
    ushort* __restrict__ WqkH, ushort* __restrict__ WqkL)
{
    __shared__ float t[64][65];
    const int id = blockIdx.x;
    const int tid = threadIdx.x;

    if (id < 1024) {            // ---- tconv hi+lo ----
        const int bx = id & 63, by = (id >> 6) & 7, bz = id >> 9;
        const float* X = bz ? y : x;
        ushort* XH = bz ? ybT : xbT;
        ushort* XL = bz ? ylT : xlT;
        const int c0 = bx * 64, r0 = by * 64;
        const int ty = tid >> 4, tx = tid & 15;
        #pragma unroll
        for (int i = 0; i < 4; ++i) {
            int r = ty + i * 16;
            float4 v = *(const float4*)&X[(size_t)(r0 + r) * N_DIM + c0 + tx * 4];
            t[r][tx * 4 + 0] = v.x; t[r][tx * 4 + 1] = v.y;
            t[r][tx * 4 + 2] = v.z; t[r][tx * 4 + 3] = v.w;
        }
        __syncthreads();
        #pragma unroll
        for (int i = 0; i < 4; ++i) {
            int nn = ty + i * 16;
            ushort4 h, l;
            float v0 = t[tx * 4 + 0][nn], v1 = t[tx * 4 + 1][nn];
            float v2 = t[tx * 4 + 2][nn], v3 = t[tx * 4 + 3][nn];
            h.x = f2bf(v0); h.y = f2bf(v1); h.z = f2bf(v2); h.w = f2bf(v3);
            l.x = f2bf(v0 - bf2f(h.x)); l.y = f2bf(v1 - bf2f(h.y));
            l.z = f2bf(v2 - bf2f(h.z)); l.w = f2bf(v3 - bf2f(h.w));
            size_t off = (size_t)(c0 + nn) * C_DIM + r0 + tx * 4;
            *(ushort4*)&XH[off] = h;
            *(ushort4*)&XL[off] = l;
        }
        return;
    }
    if (id < 1792) {            // ---- cvtw3 ----
        const int i2 = id - 1024;
        const int bx = i2 & 255, by = i2 >> 8;
        const float* in  = (by == 0) ? Wv : (by == 1) ? W1 : W2;
        ushort*      out = (by == 0) ? Wvb : (by == 1) ? W1b : W2b;
        int i = (bx * 256 + tid) * 4;
        float4 v = *(const float4*)&in[i];
        ushort4 o = { f2bf(v.x), f2bf(v.y), f2bf(v.z), f2bf(v.w) };
        *(ushort4*)&out[i] = o;
        return;
    }
    // ---- cvtqk: rows 0-63 = Wq, 64-127 = Wk ----
    {
        const int bx = id - 1792;                 // 0..63
        int i = (bx * 256 + tid) * 4;             // over [0, 65536)
        int row = i >> 9;
        const float* src = (row < 64) ? &Wq[(size_t)row * 512]
                                      : &Wk[(size_t)(row - 64) * 512];
        float4 v = *(const float4*)&src[i & 511];
        ushort4 h, l;
        h.x = f2bf(v.x); h.y = f2bf(v.y); h.z = f2bf(v.z); h.w = f2bf(v.w);
        l.x = f2bf(v.x - bf2f(h.x)); l.y = f2bf(v.y - bf2f(h.y));
        l.z = f2bf(v.z - bf2f(h.z)); l.w = f2bf(v.w - bf2f(h.w));
        *(ushort4*)&WqkH[i] = h;
        *(ushort4*)&WqkL[i] = l;
    }
}

// ---------------------------------------------------------------------------
// qkproj: bf16x3 MFMA projection. Out[m][n] = sum W[m][k] X[n][k] over the
// virtual K=1536 concat: steps 0-15 Wh.Xh, 16-31 Wh.Xl, 32-47 Wl.Xh.
// M=128 (rows 0-63 Q, 64-127 K), N=4096. grid (32 ntile, 4 kz, 2 src).
// f32 partials -> PX[(kz*2+src)*128][4096].
// ---------------------------------------------------------------------------
__global__ __launch_bounds__(256) void qkproj(
    const ushort* __restrict__ WqkH, const ushort* __restrict__ WqkL,
    const ushort* __restrict__ xbT, const ushort* __restrict__ xlT,
    const ushort* __restrict__ ybT, const ushort* __restrict__ ylT,
    float* __restrict__ PX)
{
    __shared__ ushort As[2][128 * 32];
    __shared__ ushort Bs[2][128 * 32];
    const int tid = threadIdx.x;
    const int lane = tid & 63;
    const int wid  = tid >> 6;
    const int n0  = blockIdx.x * 128;
    const int kz  = blockIdx.y;
    const int src = blockIdx.z;
    const ushort* XH = src ? ybT : xbT;
    const ushort* XL = src ? ylT : xlT;
    const int wr = (wid >> 1) * 64, wc = (wid & 1) * 64;
    const int lrow = lane >> 2;
    const int kbl  = lane & 3;

    auto stage = [&](int buf, int tt) {   // tt: global step 0..47
        const ushort* Asrc = (tt >= 32) ? WqkL : WqkH;
        const ushort* Bsrc = (tt >= 16 && tt < 32) ? XL : XH;
        const int ko = (tt & 15) * 32;
        #pragma unroll
        for (int c = wid; c < 16; c += 4) {
            if (c < 8) {
                int r = c * 16 + lrow;
                int kb = kbl ^ ((r >> 1) & 3);
                gload16(Asrc + (size_t)r * 512 + ko + kb * 8, &As[buf][c * 512]);
            } else {
                int cb = c - 8;
                int r = cb * 16 + lrow;
                int kb = kbl ^ ((r >> 1) & 3);
                gload16(Bsrc + (size_t)(n0 + r) * 512 + ko + kb * 8, &Bs[buf][cb * 512]);
            }
        }
    };

    f32x4 acc[4][4] = {};
    const int fr = lane & 15;
    const int kq = lane >> 4;
    const int t0 = kz * 12;

    stage(0, t0);
    asm volatile("s_waitcnt vmcnt(0)" ::: "memory");
    __syncthreads();
    int cur = 0;
    for (int s = 0; s < 12; ++s) {
        if (s + 1 < 12) stage(cur ^ 1, t0 + s + 1);
        short8 af[4], bf[4];
        #pragma unroll
        for (int mr = 0; mr < 4; ++mr) {
            int rA = wr + mr * 16 + fr;
            af[mr] = *(const short8*)&As[cur][rA * 32 + (kq ^ ((rA >> 1) & 3)) * 8];
        }
        #pragma unroll
        for (int nc = 0; nc < 4; ++nc) {
            int rB = wc + nc * 16 + fr;
            bf[nc] = *(const short8*)&Bs[cur][rB * 32 + (kq ^ ((rB >> 1) & 3)) * 8];
        }
        #pragma unroll
        for (int mr = 0; mr < 4; ++mr)
            #pragma unroll
            for (int nc = 0; nc < 4; ++nc)
                acc[mr][nc] = __builtin_amdgcn_mfma_f32_16x16x32_bf16(
                    af[mr], bf[nc], acc[mr][nc], 0, 0, 0);
        asm volatile("s_waitcnt vmcnt(0)" ::: "memory");
        __syncthreads();
        cur ^= 1;
    }

    const int orow = (lane >> 4) * 4;
    const int ocol = lane & 15;
    float* Of = PX + ((size_t)(kz * 2 + src) * 128) * N_DIM;
    #pragma unroll
    for (int mr = 0; mr < 4; ++mr)
        #pragma unroll
        for (int nc = 0; nc < 4; ++nc)
            #pragma unroll
            for (int j = 0; j < 4; ++j) {
                int gm = wr + mr * 16 + orow + j;
                int gn = n0 + wc + nc * 16 + ocol;
                Of[(size_t)gm * N_DIM + gn] = acc[mr][nc][j];
            }
}

// ---------------------------------------------------------------------------
// Reduce 4 PX partials, apply mask/bias/scale, split hi/lo bf16x3, write
// QF0/KF0/QF1/KF1 in score-fragment layout [256][6][64][8].
// ---------------------------------------------------------------------------
__global__ __launch_bounds__(256) void qkfinish(
    const float* __restrict__ PX,
    const float* __restrict__ s_m, const float* __restrict__ q_m,
    const float* __restrict__ bq, const float* __restrict__ bk,
    ushort* __restrict__ QF0, ushort* __restrict__ KF0,
    ushort* __restrict__ QF1, ushort* __restrict__ KF1)
{
    int gid = blockIdx.x * 256 + threadIdx.x;
    int lane = gid & 63;
    int rest = gid >> 6;
    int blk = rest & 255;
    int tensor = rest >> 8;       // 0..3
    int fr = lane & 15, quad = lane >> 4;
    int n = blk * 16 + fr;

    int srcT, rowbase, isQ;
    const float* bias;
    ushort* dst;
    float mv, scale;
    if (tensor == 0)      { srcT = 0; rowbase = 0;  isQ = 1; bias = bq; dst = QF0; scale = 0.125f; mv = s_m[n]; }
    else if (tensor == 1) { srcT = 1; rowbase = 64; isQ = 0; bias = bk; dst = KF0; scale = 1.0f;   mv = (q_m[n] > 0.8f) ? 1.0f : 0.0f; }
    else if (tensor == 2) { srcT = 1; rowbase = 0;  isQ = 1; bias = bq; dst = QF1; scale = 0.125f; mv = (q_m[n] > 0.8f) ? 1.0f : 0.0f; }
    else                  { srcT = 0; rowbase = 64; isQ = 0; bias = bk; dst = KF1; scale = 1.0f;   mv = 1.0f; }

    ushort hi0[8], lo0[8], hi1[8], lo1[8];
    #pragma unroll
    for (int j = 0; j < 8; ++j) {
        int d0 = quad * 8 + j, d1 = 32 + d0;
        float v0 = 0.0f, v1 = 0.0f;
        #pragma unroll
        for (int kz = 0; kz < 4; ++kz) {
            size_t base = ((size_t)(kz * 2 + srcT) * 128 + rowbase);
            v0 += PX[(base + d0) * N_DIM + n];
            v1 += PX[(base + d1) * N_DIM + n];
        }
        v0 = (v0 * mv + bias[d0]) * scale;
        v1 = (v1 * mv + bias[d1]) * scale;
        hi0[j] = f2bf(v0); lo0[j] = f2bf(v0 - bf2f(hi0[j]));
        hi1[j] = f2bf(v1); lo1[j] = f2bf(v1 - bf2f(hi1[j]));
    }
    auto wr8 = [&](int kstep, const ushort* v) {
        size_t base = ((size_t)(blk * 6 + kstep) * 64 + lane) * 8;
        *(ushort4*)&dst[base]     = *(const ushort4*)&v[0];
        *(ushort4*)&dst[base + 4] = *(const ushort4*)&v[4];
    };
    wr8(0, hi0); wr8(1, hi1);
    if (isQ) { wr8(2, hi0); wr8(3, hi1); wr8(4, lo0); wr8(5, lo1); }
    else     { wr8(2, lo0); wr8(3, lo1); wr8(4, hi0); wr8(5, hi1); }
}

// shared MFMA core for the two score passes (identical arithmetic order!)
__device__ __forceinline__ void scores_mfma(
    const ushort* __restrict__ QF, const ushort* __restrict__ KF,
    int m0, int n0, int wr, int wc, int lane, f32x4 acc[4][4])
{
    const int blkA0 = (m0 + wr) >> 4;
    const int blkB0 = (n0 + wc) >> 4;
    #pragma unroll
    for (int s = 0; s < 6; ++s) {
        short8 af[4], bf[4];
        #pragma unroll
        for (int mr = 0; mr < 4; ++mr)
            af[mr] = *(const short8*)&QF[((size_t)((blkA0 + mr) * 6 + s) * 64 + lane) * 8];
        #pragma unroll
        for (int nc = 0; nc < 4; ++nc)
            bf[nc] = *(const short8*)&KF[((size_t)((blkB0 + nc) * 6 + s) * 64 + lane) * 8];
        #pragma unroll
        for (int mr = 0; mr < 4; ++mr)
            #pragma unroll
            for (int nc = 0; nc < 4; ++nc)
                acc[mr][nc] = __builtin_amdgcn_mfma_f32_16x16x32_bf16(
                    af[mr], bf[nc], acc[mr][nc], 0, 0, 0);
    }
}

// ---------------------------------------------------------------------------
// vproj_p1: one launch, two independent roles.
//  id < 256  : V projection, bf16 MFMA NT <128,128>, both branches
//  id >= 256 : scores pass 1 (global max/min/sum partials + per-row max)
// ---------------------------------------------------------------------------
__global__ __launch_bounds__(256) void vproj_p1(
    const ushort* __restrict__ Wvb,
    const ushort* __restrict__ xbT, const ushort* __restrict__ ybT,
    const float* __restrict__ bv, const float* __restrict__ q_m,
    ushort* __restrict__ Vb,
    const ushort* __restrict__ QF0, const ushort* __restrict__ KF0,
    const ushort* __restrict__ QF1, const ushort* __restrict__ KF1,
    float* __restrict__ part, float* __restrict__ rowmaxp)
{
    __shared__ ushort As[2][128 * 32];
    __shared__ ushort Bs[2][128 * 32];
    __shared__ float wrm[2][128];
    __shared__ float red[256];
    const int id = blockIdx.x;
    const int tid = threadIdx.x;
    const int lane = tid & 63;
    const int wid  = tid >> 6;

    if (id < 256) {
        const int bxn = id & 31;
        const int bym = (id >> 5) & 3;
        const int br  = id >> 7;
        const ushort* A = Wvb;
        const ushort* B = br ? xbT : ybT;
        const int m0 = bym * 128, n0 = bxn * 128;
        const int wr = (wid >> 1) * 64, wc = (wid & 1) * 64;
        const int lrow = lane >> 2;
        const int kbl  = lane & 3;
        const int K = 512;

        auto stage = [&](int buf, int t) {
            #pragma unroll
            for (int c = wid; c < 16; c += 4) {
                if (c < 8) {
                    int r = c * 16 + lrow;
                    int kb = kbl ^ ((r >> 1) & 3);
                    gload16(A + (size_t)(m0 + r) * K + t * 32 + kb * 8, &As[buf][c * 512]);
                } else {
                    int cb = c - 8;
                    int r = cb * 16 + lrow;
                    int kb = kbl ^ ((r >> 1) & 3);
                    gload16(B + (size_t)(n0 + r) * K + t * 32 + kb * 8, &Bs[buf][cb * 512]);
                }
            }
        };

        f32x4 acc[4][4] = {};
        const int fr = lane & 15;
        const int kq = lane >> 4;
        stage(0, 0);
        asm volatile("s_waitcnt vmcnt(0)" ::: "memory");
        __syncthreads();
        int cur = 0;
        for (int t = 0; t < 16; ++t) {
            if (t + 1 < 16) stage(cur ^ 1, t + 1);
            short8 af[4], bf[4];
            #pragma unroll
            for (int mr = 0; mr < 4; ++mr) {
                int rA = wr + mr * 16 + fr;
                af[mr] = *(const short8*)&As[cur][rA * 32 + (kq ^ ((rA >> 1) & 3)) * 8];
            }
            #pragma unroll
            for (int nc = 0; nc < 4; ++nc) {
                int rB = wc + nc * 16 + fr;
                bf[nc] = *(const short8*)&Bs[cur][rB * 32 + (kq ^ ((rB >> 1) & 3)) * 8];
            }
            #pragma unroll
            for (int mr = 0; mr < 4; ++mr)
                #pragma unroll
                for (int nc = 0; nc < 4; ++nc)
                    acc[mr][nc] = __builtin_amdgcn_mfma_f32_16x16x32_bf16(
                        af[mr], bf[nc], acc[mr][nc], 0, 0, 0);
            asm volatile("s_waitcnt vmcnt(0)" ::: "memory");
            __syncthreads();
            cur ^= 1;
        }
        const int orow = (lane >> 4) * 4;
        const int ocol = lane & 15;
        float mcol[4];
        #pragma unroll
        for (int nc = 0; nc < 4; ++nc) {
            int gn = n0 + wc + nc * 16 + ocol;
            mcol[nc] = br ? 1.0f : ((q_m[gn] > 0.8f) ? 1.0f : 0.0f);
        }
        ushort* Obf = Vb + (size_t)br * CN;
        #pragma unroll
        for (int mr = 0; mr < 4; ++mr)
            #pragma unroll
            for (int j = 0; j < 4; ++j) {
                int gm = m0 + wr + mr * 16 + orow + j;
                float brow = bv[gm];
                #pragma unroll
                for (int nc = 0; nc < 4; ++nc) {
                    int gn = n0 + wc + nc * 16 + ocol;
                    float v = acc[mr][nc][j] * mcol[nc] + brow;
                    Obf[(size_t)gm * N_DIM + gn] = f2bf(v);
                }
            }
        return;
    }

    // ================= scores pass 1 path =================================
    {
        const int p = id - 256;
        const int bxn = p & 31;
        const int bym = (p >> 5) & 31;
        const int br  = p >> 10;
        const ushort* QF = br ? QF1 : QF0;
        const ushort* KF = br ? KF1 : KF0;
        float* pt = part + (size_t)br * 3072;
        float* rmp = rowmaxp + (size_t)br * 131072;

        const int m0 = bym * 128, n0 = bxn * 128;
        const int wr = (wid >> 1) * 64, wc = (wid & 1) * 64;
        f32x4 acc[4][4] = {};
        scores_mfma(QF, KF, m0, n0, wr, wc, lane, acc);

        float lmax = -3.4e38f, lmin = 3.4e38f, lsum = 0.0f;
        float rmx[4][4];
        #pragma unroll
        for (int mr = 0; mr < 4; ++mr)
            #pragma unroll
            for (int j = 0; j < 4; ++j) rmx[mr][j] = -3.4e38f;
        #pragma unroll
        for (int mr = 0; mr < 4; ++mr)
            #pragma unroll
            for (int nc = 0; nc < 4; ++nc)
                #pragma unroll
                for (int j = 0; j < 4; ++j) {
                    float v = acc[mr][nc][j];
                    lsum += v; lmax = fmaxf(lmax, v); lmin = fminf(lmin, v);
                    rmx[mr][j] = fmaxf(rmx[mr][j], v);
                }
        #pragma unroll
        for (int m = 1; m < 16; m <<= 1)
            #pragma unroll
            for (int mr = 0; mr < 4; ++mr)
                #pragma unroll
                for (int j = 0; j < 4; ++j)
                    rmx[mr][j] = fmaxf(rmx[mr][j], __shfl_xor(rmx[mr][j], m, 64));

        const int orow = (lane >> 4) * 4;
        if ((lane & 15) == 0) {
            #pragma unroll
            for (int mr = 0; mr < 4; ++mr)
                #pragma unroll
                for (int j = 0; j < 4; ++j)
                    wrm[wid & 1][wr + mr * 16 + orow + j] = rmx[mr][j];
        }
        __syncthreads();
        if (tid < 128) {
            float v = fmaxf(wrm[0][tid], wrm[1][tid]);
            rmp[(size_t)bxn * 4096 + m0 + tid] = v;
        }

        const int bid = bym * 32 + bxn;
        __syncthreads();
        red[tid] = lmax; __syncthreads();
        for (int s = 128; s > 0; s >>= 1) { if (tid < s) red[tid] = fmaxf(red[tid], red[tid + s]); __syncthreads(); }
        if (tid == 0) pt[bid] = red[0];
        __syncthreads();
        red[tid] = lmin; __syncthreads();
        for (int s = 128; s > 0; s >>= 1) { if (tid < s) red[tid] = fminf(red[tid], red[tid + s]); __syncthreads(); }
        if (tid == 0) pt[1024 + bid] = red[0];
        __syncthreads();
        red[tid] = lsum; __syncthreads();
        for (int s = 128; s > 0; s >>= 1) { if (tid < s) red[tid] += red[tid + s]; __syncthreads(); }
        if (tid == 0) pt[2048 + bid] = red[0];
    }
}

// thr per branch (tiny separate kernel — folding caused a VGPR cliff, r7)
__global__ __launch_bounds__(256) void stats_fin2(
    const float* __restrict__ part, float* __restrict__ stats)
{
    const int br = blockIdx.x;
    part += (size_t)br * 3072;
    __shared__ float rmax[256], rmin[256];
    __shared__ double rsum[256];
    int tid = threadIdx.x;
    float m1 = -3.4e38f, m2 = 3.4e38f; double s = 0.0;
    for (int i = tid; i < 1024; i += 256) {
        m1 = fmaxf(m1, part[i]);
        m2 = fminf(m2, part[1024 + i]);
        s += (double)part[2048 + i];
    }
    rmax[tid] = m1; rmin[tid] = m2; rsum[tid] = s;
    __syncthreads();
    for (int st = 128; st > 0; st >>= 1) {
        if (tid < st) {
            rmax[tid] = fmaxf(rmax[tid], rmax[tid + st]);
            rmin[tid] = fminf(rmin[tid], rmin[tid + st]);
            rsum[tid] += rsum[tid + st];
        }
        __syncthreads();
    }
    if (tid == 0) {
        float stat = (br == 0) ? rmax[0] : rmin[0];
        float mean = (float)(rsum[0] / (double)NN_TOT);
        stats[br] = 0.5f * (stat + mean);
    }
}

// ---------------------------------------------------------------------------
// pass 2 (z-batched): folded row_fin; recompute scores, write e = exp(s-m)
// bf16 + rowsum partials.
// ---------------------------------------------------------------------------
__global__ __launch_bounds__(256) void scores_pass2(
    const ushort* __restrict__ QF0, const ushort* __restrict__ KF0,
    const ushort* __restrict__ QF1, const ushort* __restrict__ KF1,
    const float* __restrict__ stats, const float* __restrict__ rowmaxp,
    ushort* __restrict__ Pe, float* __restrict__ rowsump)
{
    const int br = blockIdx.z;
    const ushort* QF = br ? QF1 : QF0;
    const ushort* KF = br ? KF1 : KF0;
    ushort* P = Pe + (size_t)br * NN;
    rowsump += (size_t)br * 131072;
    rowmaxp += (size_t)br * 131072;

    const int tid = threadIdx.x;
    const int lane = tid & 63, wid = tid >> 6;
    const int m0 = blockIdx.y * 128, n0 = blockIdx.x * 128;
    const int wr = (wid >> 1) * 64, wc = (wid & 1) * 64;
    const float thr = stats[br];

    __shared__ float rowmL[128];
    if (tid < 128) {
        int r = m0 + tid;
        float m = -3.4e38f;
        #pragma unroll 8
        for (int b = 0; b < 32; ++b)
            m = fmaxf(m, rowmaxp[(size_t)b * 4096 + r]);
        rowmL[tid] = (m >= thr) ? m : -1e30f;
    }
    __syncthreads();

    f32x4 acc[4][4] = {};
    scores_mfma(QF, KF, m0, n0, wr, wc, lane, acc);

    const int orow = (lane >> 4) * 4;
    const int ocol = lane & 15;
    float rm[4][4], rs[4][4];
    #pragma unroll
    for (int mr = 0; mr < 4; ++mr)
        #pragma unroll
        for (int j = 0; j < 4; ++j) {
            rm[mr][j] = rowmL[wr + mr * 16 + orow + j];
            rs[mr][j] = 0.0f;
        }
    #pragma unroll
    for (int mr = 0; mr < 4; ++mr)
        #pragma unroll
        for (int nc = 0; nc < 4; ++nc)
            #pragma unroll
            for (int j = 0; j < 4; ++j) {
                float s = acc[mr][nc][j];
                float m = rm[mr][j];
                float e = (s < thr) ? 0.0f : __expf(s - m);
                if (m < -1e29f) e = 1.0f;          // fully-masked row -> uniform
                ushort h = f2bf(e);
                rs[mr][j] += bf2f(h);
                P[(size_t)(m0 + wr + mr * 16 + orow + j) * N_DIM
                  + n0 + wc + nc * 16 + ocol] = h;
            }
    #pragma unroll
    for (int m = 1; m < 16; m <<= 1)
        #pragma unroll
        for (int mr = 0; mr < 4; ++mr)
            #pragma unroll
            for (int j = 0; j < 4; ++j)
                rs[mr][j] += __shfl_xor(rs[mr][j], m, 64);

    __shared__ float wrs[2][128];
    if ((lane & 15) == 0) {
        #pragma unroll
        for (int mr = 0; mr < 4; ++mr)
            #pragma unroll
            for (int j = 0; j < 4; ++j)
                wrs[wid & 1][wr + mr * 16 + orow + j] = rs[mr][j];
    }
    __syncthreads();
    if (tid < 128)
        rowsump[(size_t)blockIdx.x * 4096 + m0 + tid] =
            wrs[0][tid] + wrs[1][tid];
}

// ---------------------------------------------------------------------------
// Generic bf16 MFMA NT GEMM (round-5 proven).
// ---------------------------------------------------------------------------
template<int BM, int BN>
__global__ __launch_bounds__(256) void mfma_g(
    const ushort* __restrict__ A0, const ushort* __restrict__ A1,
    const ushort* __restrict__ B0, const ushort* __restrict__ B1,
    void* __restrict__ Out, size_t outBrStride,
    int M, int N, int K, int kLen, int nkz, int swapxy,
    const float* __restrict__ bias, int biasMode,
    const float* __restrict__ mask0, int mm0,
    const float* __restrict__ mask1, int mm1,
    int doRelu, int outBf16, float* __restrict__ lnp)
{
    constexpr int WAVES_M = BM / 64;
    constexpr int WAVES_N = 4 / WAVES_M;
    constexpr int WN = BN / WAVES_N;
    constexpr int FM = 4;
    constexpr int FN = WN / 16;
    constexpr int NCHUNK = (BM + BN) / 16;

    __shared__ ushort As[2][BM * 32];
    __shared__ ushort Bs[2][BN * 32];
    const int tid  = threadIdx.x;
    const int lane = tid & 63;
    const int wid  = tid >> 6;
    const int z  = blockIdx.z;
    const int br = z / nkz;
    const int kz = z % nkz;
    const ushort* A = br ? A1 : A0;
    const ushort* B = br ? B1 : B0;
    const float* mask = br ? mask1 : mask0;
    const int maskMode = br ? mm1 : mm0;

    const int bxm = swapxy ? blockIdx.x : blockIdx.y;
    const int bxn = swapxy ? blockIdx.y : blockIdx.x;
    const int m0 = bxm * BM, n0 = bxn * BN;
    const int wm = wid / WAVES_N, wn = wid % WAVES_N;
    const int wr = wm * 64, wc = wn * WN;
    const int kOff = kz * kLen;
    const int lrow = lane >> 2;
    const int kbl  = lane & 3;

    auto stage = [&](int buf, int t) {
        #pragma unroll
        for (int c = wid; c < NCHUNK; c += 4) {
            if (c < BM / 16) {
                int r = c * 16 + lrow;
                int kb = kbl ^ ((r >> 1) & 3);
                gload16(A + (size_t)(m0 + r) * K + kOff + t * 32 + kb * 8,
                        &As[buf][c * 512]);
            } else {
                int cb = c - BM / 16;
                int r = cb * 16 + lrow;
                int kb = kbl ^ ((r >> 1) & 3);
                gload16(B + (size_t)(n0 + r) * K + kOff + t * 32 + kb * 8,
                        &Bs[buf][cb * 512]);
            }
        }
    };

    f32x4 acc[FM][FN] = {};
    const int fr = lane & 15;
    const int kq = lane >> 4;
    const int nt = kLen / 32;

    stage(0, 0);
    asm volatile("s_waitcnt vmcnt(0)" ::: "memory");
    __syncthreads();
    int cur = 0;
    for (int t = 0; t < nt; ++t) {
        if (t + 1 < nt) stage(cur ^ 1, t + 1);
        short8 af[FM], bf[FN];
        #pragma unroll
        for (int mr = 0; mr < FM; ++mr) {
            int rA = wr + mr * 16 + fr;
            af[mr] = *(const short8*)&As[cur][rA * 32 + (kq ^ ((rA >> 1) & 3)) * 8];
        }
        #pragma unroll
        for (int nc = 0; nc < FN; ++nc) {
            int rB = wc + nc * 16 + fr;
            bf[nc] = *(const short8*)&Bs[cur][rB * 32 + (kq ^ ((rB >> 1) & 3)) * 8];
        }
        #pragma unroll
        for (int mr = 0; mr < FM; ++mr)
            #pragma unroll
            for (int nc = 0; nc < FN; ++nc)
                acc[mr][nc] = __builtin_amdgcn_mfma_f32_16x16x32_bf16(
                    af[mr], bf[nc], acc[mr][nc], 0, 0, 0);
        asm volatile("s_waitcnt vmcnt(0)" ::: "memory");
        __syncthreads();
        cur ^= 1;
    }

    const int orow = (lane >> 4) * 4;
    const int ocol = lane & 15;

    if (nkz > 1) {
        float* Of = (float*)Out + (size_t)z * M * N;
        #pragma unroll
        for (int mr = 0; mr < FM; ++mr)
            #pragma unroll
            for (int nc = 0; nc < FN; ++nc)
                #pragma unroll
                for (int j = 0; j < 4; ++j) {
                    int gm = m0 + wr + mr * 16 + orow + j;
                    int gn = n0 + wc + nc * 16 + ocol;
                    Of[(size_t)gm * N + gn] = acc[mr][nc][j];
                }
        return;
    }

    float mcol[FN], bcol[FN];
    #pragma unroll
    for (int nc = 0; nc < FN; ++nc) {
        int gn = n0 + wc + nc * 16 + ocol;
        mcol[nc] = (maskMode == 0) ? 1.0f
                 : (maskMode == 1) ? mask[gn]
                                   : (mask[gn] > 0.8f ? 1.0f : 0.0f);
        bcol[nc] = (biasMode == 2) ? bias[gn] : 0.0f;
    }
    ushort* Obf = (ushort*)Out + (size_t)br * outBrStride;
    float*  Of  = (float*)Out + (size_t)br * outBrStride;
    float lsum = 0.0f, lsq = 0.0f;
    #pragma unroll
    for (int mr = 0; mr < FM; ++mr) {
        #pragma unroll
        for (int j = 0; j < 4; ++j) {
            int gm = m0 + wr + mr * 16 + orow + j;
            float brow = (biasMode == 1) ? bias[gm] : 0.0f;
            #pragma unroll
            for (int nc = 0; nc < FN; ++nc) {
                int gn = n0 + wc + nc * 16 + ocol;
                float v = acc[mr][nc][j] * mcol[nc] + brow + bcol[nc];
                if (doRelu) v = fmaxf(v, 0.0f);
                if (outBf16) Obf[(size_t)gm * N + gn] = f2bf(v);
                else         Of[(size_t)gm * N + gn] = v;
                lsum += v; lsq = fmaf(v, v, lsq);
            }
        }
    }
    if (lnp) {
        __shared__ float redS[256], redQ[256];
        redS[tid] = lsum; redQ[tid] = lsq;
        __syncthreads();
        for (int s = 128; s > 0; s >>= 1) {
            if (tid < s) { redS[tid] += redS[tid + s]; redQ[tid] += redQ[tid + s]; }
            __syncthreads();
        }
        if (tid == 0) {
            int fb = blockIdx.y * gridDim.x + blockIdx.x;
            lnp[br * 512 + fb] = redS[0];
            lnp[br * 512 + 256 + fb] = redQ[0];
        }
    }
}

// sum 2 split-K partials * per-row softmax scale -> bf16 (z-batched)
__global__ __launch_bounds__(256) void reduce2row(
    const float* __restrict__ P4, const float* __restrict__ rowsump,
    ushort* __restrict__ O)
{
    const int br = blockIdx.y;
    const int tid = threadIdx.x;
    const int r0 = blockIdx.x * 2;
    __shared__ float invL[2];
    if (tid < 64) {
        int rw = tid >> 5, b = tid & 31;
        float s = rowsump[(size_t)br * 131072 + (size_t)b * 4096 + r0 + rw];
        #pragma unroll
        for (int m = 1; m < 32; m <<= 1) s += __shfl_xor(s, m, 64);
        if (b == 0) invL[rw] = 1.0f / s;
    }
    __syncthreads();
    int i = (blockIdx.x * 256 + tid) * 4;
    float sc = invL[(i >> 9) & 1];
    float4 a = *(const float4*)&P4[(size_t)(br * 2 + 0) * SZO + i];
    float4 b = *(const float4*)&P4[(size_t)(br * 2 + 1) * SZO + i];
    ushort4 o;
    o.x = f2bf((a.x + b.x) * sc);
    o.y = f2bf((a.y + b.y) * sc);
    o.z = f2bf((a.z + b.z) * sc);
    o.w = f2bf((a.w + b.w) * sc);
    *(ushort4*)&O[(size_t)br * SZO + i] = o;
}

// ---------------------------------------------------------------------------
// gate_write with folded ln_fin (identical tree order -> bitwise-same stats)
// ---------------------------------------------------------------------------
__global__ __launch_bounds__(256) void gate_write(
    const float* __restrict__ H2, const float* __restrict__ lnp,
    const float* __restrict__ gamma, const float* __restrict__ beta,
    const float* __restrict__ x, const float* __restrict__ y,
    const float* __restrict__ s_m, const float* __restrict__ q_m,
    float* __restrict__ out)
{
    const int br = blockIdx.y;
    const int tid = threadIdx.x;
    __shared__ double rs[256], rq[256];
    rs[tid] = (double)lnp[(size_t)br * 512 + tid];
    rq[tid] = (double)lnp[(size_t)br * 512 + 256 + tid];
    __syncthreads();
    for (int st = 128; st > 0; st >>= 1) {
        if (tid < st) { rs[tid] += rs[tid + st]; rq[tid] += rq[tid + st]; }
        __syncthreads();
    }
    double muD = rs[0] / (double)CN;
    double varD = rq[0] / (double)CN - muD * muD;
    float mu = (float)muD;
    float rstd = (float)(1.0 / sqrt(varD + 1e-5));

    size_t i = ((size_t)blockIdx.x * 256 + tid) * 4;
    int n = (int)(i & (N_DIM - 1));
    float4 h = *(const float4*)&H2[(size_t)br * CN + i];
    float4 g = *(const float4*)&gamma[i];
    float4 b = *(const float4*)&beta[i];
    const float* resid = br ? y : x;
    float4 r = *(const float4*)&resid[i];
    float vals[4] = { h.x, h.y, h.z, h.w };
    float gs[4] = { g.x, g.y, g.z, g.w };
    float bs[4] = { b.x, b.y, b.z, b.w };
    float rsv[4] = { r.x, r.y, r.z, r.w };
    float os[4];
    #pragma unroll
    for (int j = 0; j < 4; ++j) {
        float mv = br ? ((q_m[n + j] > 0.8f) ? 1.0f : 0.0f) : s_m[n + j];
        float normed = (vals[j] - mu) * rstd * gs[j] + bs[j];
        os[j] = normed * mv + rsv[j] * (1.0f - mv);
    }
    float4 o; o.x = os[0]; o.y = os[1]; o.z = os[2]; o.w = os[3];
    *(float4*)&out[(size_t)br * CN + i] = o;
}

// ---------------------------------------------------------------------------
extern "C" void kernel_launch(void* const* d_in, const int* in_sizes, int n_in,
                              void* d_out, int out_size, void* d_ws, size_t ws_size,
                              hipStream_t stream)
{
    const float* x     = (const float*)d_in[0];
    const float* y     = (const float*)d_in[1];
    const float* s_m   = (const float*)d_in[2];
    const float* q_m   = (const float*)d_in[3];
    const float* Wq    = (const float*)d_in[4];
    const float* bq    = (const float*)d_in[5];
    const float* Wk    = (const float*)d_in[6];
    const float* bk    = (const float*)d_in[7];
    const float* Wv    = (const float*)d_in[8];
    const float* bv    = (const float*)d_in[9];
    const float* W1    = (const float*)d_in[10];
    const float* b1    = (const float*)d_in[11];
    const float* W2    = (const float*)d_in[12];
    const float* b2    = (const float*)d_in[13];
    const float* gamma = (const float*)d_in[14];
    const float* beta  = (const float*)d_in[15];
    float* out = (float*)d_out;

    // ---- workspace layout ----
    float* ws = (float*)d_ws;
    float*  R1    = ws;                         // 8,388,608 f
    float*  PX    = R1;                         // [4][2][128][4096] (4,194,304 f)
    float*  P4    = R1;                         // [4][4096][512] split-K partials
    ushort* QF0   = (ushort*)(R1 + 4194304);
    ushort* KF0   = QF0 + 786432;
    ushort* QF1   = KF0 + 786432;
    ushort* KF1   = QF1 + 786432;
    float*  SMALL = R1 + 8388608;
    float*  PART  = SMALL;                      // [2][3072]
    float*  RMAXP = PART + 6144;                // [2][131072]
    float*  RSUMP = RMAXP + 262144;             // [2][131072]
    float*  LNP   = RSUMP + 262144;             // [2][512]
    float*  STATS = LNP + 1024;                 // 64
    ushort* WqkH  = (ushort*)(STATS + 64);      // [128][512]
    ushort* WqkL  = WqkH + 65536;               // [128][512]
    ushort* Wvb   = WqkL + 65536;
    ushort* W1b   = Wvb + 262144;
    ushort* W2b   = W1b + 262144;
    ushort* Vb    = W2b + 262144;               // [2][512][4096]
    ushort* R2    = Vb + 4194304;
    ushort* xbT   = R2;                         // [4096][512] hi (dead after V-proj)
    ushort* ybT   = R2 + 2097152;
    ushort* xlT   = R2 + 4194304;               // lo planes (dead after qkproj)
    ushort* ylT   = R2 + 6291456;
    ushort* Pe    = R2;                         // [2][4096][4096]
    ushort* O1T   = R2;                         // [2][4096][512] (Pe dead)
    ushort* H1T   = R2 + 4194304;               // [2][4096][512]
    float*  H2    = (float*)(R2 + 8388608);     // [2][512][4096] f32

    // 1. setup: tconv hi/lo + weight cvt + Wqk hi/lo (one memory-bound launch)
    setup2<<<1856, 256, 0, stream>>>(
        x, y, xbT, xlT, ybT, ylT, Wv, W1, W2, Wvb, W1b, W2b,
        Wq, Wk, WqkH, WqkL);

    // 2. Q/K projection via bf16x3 MFMA (split-K x4, both srcs) -> f32 PX
    qkproj<<<dim3(32, 4, 2), 256, 0, stream>>>(
        WqkH, WqkL, xbT, xlT, ybT, ylT, PX);

    // 3. Q/K finish: reduce 4 partials, mask/bias/scale, bf16x3 fragments
    qkfinish<<<256, 256, 0, stream>>>(PX, s_m, q_m, bq, bk, QF0, KF0, QF1, KF1);

    // 4. V-proj (256 blocks) backfilled under scores pass 1 (2048 blocks)
    vproj_p1<<<2304, 256, 0, stream>>>(
        Wvb, xbT, ybT, bv, q_m, Vb, QF0, KF0, QF1, KF1, PART, RMAXP);

    // 5. threshold finalize
    stats_fin2<<<2, 256, 0, stream>>>(PART, STATS);

    // 6. scores pass 2 (folded row_fin)
    scores_pass2<<<dim3(32, 32, 2), 256, 0, stream>>>(
        QF0, KF0, QF1, KF1, STATS, RMAXP, Pe, RSUMP);

    // 7. O1T = Pe . Vb^T (split-K x2, 128x128, swapped axes for L2 locality)
    mfma_g<128, 128><<<dim3(32, 4, 4), 256, 0, stream>>>(
        Pe, Pe + NN, Vb, Vb + CN, P4, 0,
        4096, 512, 4096, 2048, 2, 1, nullptr, 0, nullptr, 0, nullptr, 0, 0, 0, nullptr);

    // 8. split-K reduce + softmax normalize (folded rsum_fin)
    reduce2row<<<dim3(2048, 2), 256, 0, stream>>>(P4, RSUMP, O1T);

    // 9. MLP1: H1T = relu(O1T . W1^T + b1)
    mfma_g<128, 64><<<dim3(32, 8, 2), 256, 0, stream>>>(
        O1T, O1T + SZO, W1b, W1b, H1T, (size_t)SZO,
        4096, 512, 512, 512, 1, 1, b1, 2, nullptr, 0, nullptr, 0, 1, 1, nullptr);

    // 10. MLP2: H2 = W2 . H1T^T + b2 -> f32, fused LN partials
    mfma_g<64, 128><<<dim3(32, 8, 2), 256, 0, stream>>>(
        W2b, W2b, H1T, H1T + SZO, H2, (size_t)CN,
        512, 4096, 512, 512, 1, 0, b2, 1, nullptr, 0, nullptr, 0, 0, 0, LNP);

    // 11. gate + folded LayerNorm finalize
    gate_write<<<dim3(2048, 2), 256, 0, stream>>>(
        H2, LNP, gamma, beta, x, y, s_m, q_m, out);
}